// Round 5
// baseline (2070.006 us; speedup 1.0000x reference)
//
#include <hip/hip_runtime.h>
#include <math.h>

// KERNEL_WIDTH = sqrt(9/pi) = 1.6925687506432297
#define KW2_F  2.8647889756541161f   // (9/pi)
#define KW_INV 0.5908179502964271f   // 1/KW
#define RW_F   1.6926f               // slightly >= KW (safe superset bound)

__device__ __forceinline__ float fast_sqrtf(float x) {
    return __builtin_amdgcn_sqrtf(x);   // raw v_sqrt_f32, ~1 ulp, no denorm guard
}

// ---------------------------------------------------------------------------
// k-chunked (x4, float4) tube-of-response for one LOR. Requires s2 == 1 and
// n2 % 4 == 0. img indexed as jx*s0 + jy*s1 + k.
// Iterating all in-bounds taps within radius RW of the segment and clamping
// w at 0 reproduces the reference 5x5-window sum exactly: any tap with w>0
// has |jx-fx| < KW, and |jx-round(fx)| <= |jx-fx|+0.5 < 2.19 -> inside window.
// ---------------------------------------------------------------------------
__device__ __forceinline__
float tor_lor4(const float* __restrict__ img,
               const float* __restrict__ L,
               float lo0, float lo1, float lo2,
               float vs0, float vs1, float vs2,
               int n0, int n1, int n2, int s0, int s1)
{
    const float inv_vs0 = 1.0f / vs0;
    const float inv_vs1 = 1.0f / vs1;

    const float p1x = L[0], p1y = L[1], p1z = L[2];
    const float p2x = L[3], p2y = L[4], p2z = L[5];
    const float dx = p2x - p1x, dy = p2y - p1y, dz = p2z - p1z;
    const float len = sqrtf(dx * dx + dy * dy + dz * dz);
    const float inv_dz = 1.0f / dz;
    const float step = vs2 * len * fabsf(inv_dz);

    float acc0 = 0.0f, acc1 = 0.0f, acc2 = 0.0f, acc3 = 0.0f;

    for (int k0 = 0; k0 < n2; k0 += 4) {
        float fx[4], fy[4];
#pragma unroll
        for (int j = 0; j < 4; ++j) {
            const float zc = lo2 + ((float)(k0 + j) + 0.5f) * vs2;
            const float t  = (zc - p1z) * inv_dz;
            fx[j] = (fmaf(t, dx, p1x) - lo0) * inv_vs0 - 0.5f;
            fy[j] = (fmaf(t, dy, p1y) - lo1) * inv_vs1 - 0.5f;
        }
        // fx,fy affine in k -> chunk extremes at endpoints.
        const float fxmin = fminf(fx[0], fx[3]), fxmax = fmaxf(fx[0], fx[3]);
        const float fymin = fminf(fy[0], fy[3]), fymax = fmaxf(fy[0], fy[3]);
        const int xlo = max(0,      (int)ceilf (fxmin - RW_F));
        const int xhi = min(n0 - 1, (int)floorf(fxmax + RW_F));
        const int ylo = max(0,      (int)ceilf (fymin - RW_F));
        const int yhi = min(n1 - 1, (int)floorf(fymax + RW_F));

        for (int jx = xlo; jx <= xhi; ++jx) {
            float ddx2[4];
#pragma unroll
            for (int j = 0; j < 4; ++j) {
                const float dxx = (float)jx - fx[j];
                ddx2[j] = dxx * dxx;
            }
            const float rowmin =
                fminf(fminf(ddx2[0], ddx2[1]), fminf(ddx2[2], ddx2[3]));
            if (rowmin >= KW2_F) continue;   // whole row weightless

            const float* rowp = img + jx * s0 + k0;

            for (int jy = ylo; jy <= yhi; ++jy) {
                float d2[4];
#pragma unroll
                for (int j = 0; j < 4; ++j) {
                    const float dyy = (float)jy - fy[j];
                    d2[j] = fmaf(dyy, dyy, ddx2[j]);
                }
                const float dmin =
                    fminf(fminf(d2[0], d2[1]), fminf(d2[2], d2[3]));
                if (dmin < KW2_F) {
                    const float4 v =
                        *reinterpret_cast<const float4*>(rowp + jy * s1);
                    float wg[4];
#pragma unroll
                    for (int j = 0; j < 4; ++j)
                        wg[j] = fmaxf(0.0f, fmaf(-fast_sqrtf(d2[j]), KW_INV, 1.0f));
                    acc0 = fmaf(wg[0], v.x, acc0);
                    acc1 = fmaf(wg[1], v.y, acc1);
                    acc2 = fmaf(wg[2], v.z, acc2);
                    acc3 = fmaf(wg[3], v.w, acc3);
                }
            }
        }
    }
    return (acc0 + acc1 + acc2 + acc3) * step;
}

// Scalar guarded fallback (any strides / any n2).
__device__ __forceinline__
float tor_lor_s(const float* __restrict__ img,
                const float* __restrict__ L,
                float lo0, float lo1, float lo2,
                float vs0, float vs1, float vs2,
                int n0, int n1, int n2, int s0, int s1, int s2)
{
    const float inv_vs0 = 1.0f / vs0;
    const float inv_vs1 = 1.0f / vs1;
    const float p1x = L[0], p1y = L[1], p1z = L[2];
    const float p2x = L[3], p2y = L[4], p2z = L[5];
    const float dx = p2x - p1x, dy = p2y - p1y, dz = p2z - p1z;
    const float len = sqrtf(dx * dx + dy * dy + dz * dz);
    const float inv_dz = 1.0f / dz;
    const float step = vs2 * len * fabsf(inv_dz);

    float acc_total = 0.0f;
    for (int k = 0; k < n2; ++k) {
        const float zc = lo2 + ((float)k + 0.5f) * vs2;
        const float t  = (zc - p1z) * inv_dz;
        const float fx = (fmaf(t, dx, p1x) - lo0) * inv_vs0 - 0.5f;
        const float fy = (fmaf(t, dy, p1y) - lo1) * inv_vs1 - 0.5f;
        const int ix = (int)rintf(fx);
        const int iy = (int)rintf(fy);
        const int kb = k * s2;
        float acc = 0.0f;
#pragma unroll
        for (int o0 = -2; o0 <= 2; ++o0) {
            const int jx = ix + o0;
            if ((unsigned)jx >= (unsigned)n0) continue;
            const float dxx  = (float)jx - fx;
            const float ddx2 = dxx * dxx;
            if (ddx2 >= KW2_F) continue;
            const int xb = jx * s0 + kb;
#pragma unroll
            for (int o1 = -2; o1 <= 2; ++o1) {
                const int jy = iy + o1;
                if ((unsigned)jy >= (unsigned)n1) continue;
                const float dyy = (float)jy - fy;
                const float d2  = fmaf(dyy, dyy, ddx2);
                if (d2 < KW2_F) {
                    const float w = fmaf(-fast_sqrtf(d2), KW_INV, 1.0f);
                    acc = fmaf(w, img[xb + jy * s1], acc);
                }
            }
        }
        acc_total += acc;
    }
    return acc_total * step;
}

// ---------------------------------------------------------------------------
// Slope-bucket counting sort (convergence: same-bucket lanes share loop trip
// counts). Key = quantized (|d0/d2|, |d1/d2|), 16x16 = 256 buckets per set.
// ---------------------------------------------------------------------------
__device__ __forceinline__ int lor_key(const float* __restrict__ L)
{
    const float a0 = fabsf(L[3] - L[0]);
    const float a1 = fabsf(L[4] - L[1]);
    const float a2 = fabsf(L[5] - L[2]);
    const float inv = 1.0f / a2;
    const int qx = min(15, (int)(a0 * inv * 21.333333f));  // 16 bins over [0,0.75]
    const int qy = min(15, (int)(a1 * inv * 21.333333f));
    return qx * 16 + qy;
}

__global__ __launch_bounds__(256)
void zero_bins(unsigned* __restrict__ bins, int n)
{
    const int t = blockIdx.x * 256 + threadIdx.x;
    if (t < n) bins[t] = 0u;
}

__global__ __launch_bounds__(256)
void hist_kernel(const float* __restrict__ xl, const float* __restrict__ yl,
                 const float* __restrict__ zl,
                 int nx, int ny, int nz, unsigned* __restrict__ hist)
{
    const int t = blockIdx.x * 256 + threadIdx.x;
    const float* L; int set;
    if (t < nx)                { L = xl + 6 * (size_t)t;              set = 0; }
    else if (t < nx + ny)      { L = yl + 6 * (size_t)(t - nx);       set = 1; }
    else if (t < nx + ny + nz) { L = zl + 6 * (size_t)(t - nx - ny);  set = 2; }
    else return;
    atomicAdd(&hist[set * 256 + lor_key(L)], 1u);
}

__global__ __launch_bounds__(256)
void scan_bins(const unsigned* __restrict__ hist, unsigned* __restrict__ offs)
{
    __shared__ unsigned h[768];
    for (int t = threadIdx.x; t < 768; t += 256) h[t] = hist[t];
    __syncthreads();
    if (threadIdx.x < 3) {
        unsigned run = 0;
        const int b = threadIdx.x * 256;
        for (int k = 0; k < 256; ++k) { const unsigned c = h[b + k]; h[b + k] = run; run += c; }
    }
    __syncthreads();
    for (int t = threadIdx.x; t < 768; t += 256) offs[t] = h[t];
}

__global__ __launch_bounds__(256)
void scatter_kernel(const float* __restrict__ xl, const float* __restrict__ yl,
                    const float* __restrict__ zl,
                    int nx, int ny, int nz,
                    unsigned* __restrict__ offs, unsigned* __restrict__ perm)
{
    const int t = blockIdx.x * 256 + threadIdx.x;
    const float* L; int set, i, base;
    if (t < nx)                { L = xl + 6 * (size_t)t;             set = 0; i = t;            base = 0;       }
    else if (t < nx + ny)      { L = yl + 6 * (size_t)(t - nx);      set = 1; i = t - nx;       base = nx;      }
    else if (t < nx + ny + nz) { L = zl + 6 * (size_t)(t - nx - ny); set = 2; i = t - nx - ny;  base = nx + ny; }
    else return;
    const unsigned pos = atomicAdd(&offs[set * 256 + lor_key(L)], 1u);
    perm[base + pos] = (unsigned)i;
}

// ---------------------------------------------------------------------------
// Fused launch: block ranges pick the LOR set. FOUR==1 -> float4 path with
// slope-sorted perm indirection (s2==1 for all sets; x uses transposed copy).
// ---------------------------------------------------------------------------
template<int FOUR>
__global__ __launch_bounds__(128)
void proj_fused(const float* __restrict__ imgZ,
                const float* __restrict__ imgX,
                const float* __restrict__ xlors,
                const float* __restrict__ ylors,
                const float* __restrict__ zlors,
                const float* __restrict__ center,
                const float* __restrict__ size_,
                const unsigned* __restrict__ perm,
                float* __restrict__ out,
                int nx, int ny, int nz,
                int nbx, int nby, int G,
                int xs0, int xs1, int xs2)  // x-set strides (scalar path)
{
    const int b = blockIdx.x;
    const int G2 = G * G;

    const float* img;
    const float* lors;
    float* op;
    int a0, a1, a2, s0, s1, s2;

    if (b < nbx) {            // px: perm (2,0,1)
        const int idx = b * 128 + threadIdx.x;
        if (idx >= nx) return;
        const int i = FOUR ? (int)perm[idx] : idx;
        img = FOUR ? imgX : imgZ;
        lors = xlors + 6 * (size_t)i;  op = out + i;
        a0 = 2; a1 = 0; a2 = 1;
        if (FOUR) { s0 = G2; s1 = G; s2 = 1; }
        else      { s0 = xs0; s1 = xs1; s2 = xs2; }
    } else if (b < nbx + nby) {  // py: perm (1,0,2)
        const int idx = (b - nbx) * 128 + threadIdx.x;
        if (idx >= ny) return;
        const int i = FOUR ? (int)perm[nx + idx] : idx;
        img = imgZ; lors = ylors + 6 * (size_t)i;  op = out + nx + i;
        a0 = 1; a1 = 0; a2 = 2;  s0 = G; s1 = G2; s2 = 1;
    } else {                     // pz: identity
        const int idx = (b - nbx - nby) * 128 + threadIdx.x;
        if (idx >= nz) return;
        const int i = FOUR ? (int)perm[nx + ny + idx] : idx;
        img = imgZ; lors = zlors + 6 * (size_t)i;  op = out + nx + ny + i;
        a0 = 0; a1 = 1; a2 = 2;  s0 = G2; s1 = G; s2 = 1;
    }

    const float S0 = size_[a0], S1 = size_[a1], S2 = size_[a2];
    const float vs0 = S0 / (float)G, vs1 = S1 / (float)G, vs2 = S2 / (float)G;
    const float lo0 = center[a0] - 0.5f * S0;
    const float lo1 = center[a1] - 0.5f * S1;
    const float lo2 = center[a2] - 0.5f * S2;

    float r;
    if (FOUR)
        r = tor_lor4(img, lors, lo0, lo1, lo2, vs0, vs1, vs2,
                     G, G, G, s0, s1);
    else
        r = tor_lor_s(img, lors, lo0, lo1, lo2, vs0, vs1, vs2,
                      G, G, G, s0, s1, s2);
    *op = r;
}

// 2D transpose in[R][C] -> out[C][R]; Px[c,i0,i1] = image[i0,i1,c]
// giving the x-perm with strides (G^2, G, 1). R, C divisible by 32.
__global__ __launch_bounds__(256)
void transpose_RC(const float* __restrict__ in, float* __restrict__ outp,
                  int R, int C)
{
    __shared__ float tile[32][33];
    const int rt = blockIdx.x * 32;
    const int ct = blockIdx.y * 32;
    const int tx = threadIdx.x;
    const int ty = threadIdx.y;   // block (32,8)
#pragma unroll
    for (int j = 0; j < 32; j += 8)
        tile[ty + j][tx] = in[(size_t)(rt + ty + j) * C + (ct + tx)];
    __syncthreads();
#pragma unroll
    for (int j = 0; j < 32; j += 8)
        outp[(size_t)(ct + ty + j) * R + (rt + tx)] = tile[tx][ty + j];
}

extern "C" void kernel_launch(void* const* d_in, const int* in_sizes, int n_in,
                              void* d_out, int out_size, void* d_ws, size_t ws_size,
                              hipStream_t stream)
{
    const float* img    = (const float*)d_in[0];
    const float* center = (const float*)d_in[2];
    const float* size_  = (const float*)d_in[3];
    const float* xlors  = (const float*)d_in[4];
    const float* ylors  = (const float*)d_in[5];
    const float* zlors  = (const float*)d_in[6];
    float* out = (float*)d_out;

    const int nx = in_sizes[4] / 6;
    const int ny = in_sizes[5] / 6;
    const int nz = in_sizes[6] / 6;
    const int ntot = nx + ny + nz;

    int G = (int)lround(cbrt((double)in_sizes[0]));
    const int G2 = G * G;

    const int B = 128;
    const int nbx = (nx + B - 1) / B;
    const int nby = (ny + B - 1) / B;
    const int nbz = (nz + B - 1) / B;
    const int nb  = nbx + nby + nbz;

    // Workspace layout: [Px: G^3 f32][hist: 768 u32][offs: 768 u32][perm: ntot u32]
    const size_t pxBytes   = (size_t)G * G2 * sizeof(float);
    const size_t needBytes = pxBytes + 2 * 768 * sizeof(unsigned)
                           + (size_t)ntot * sizeof(unsigned);
    const bool fast = (G % 32 == 0) && (ws_size >= needBytes);

    if (fast) {
        float*    Px   = (float*)d_ws;
        unsigned* hist = (unsigned*)((char*)d_ws + pxBytes);
        unsigned* offs = hist + 768;
        unsigned* perm = offs + 768;

        transpose_RC<<<dim3(G2 / 32, G / 32), dim3(32, 8), 0, stream>>>(
            img, Px, G2, G);

        zero_bins<<<3, 256, 0, stream>>>(hist, 768);
        hist_kernel<<<(ntot + 255) / 256, 256, 0, stream>>>(
            xlors, ylors, zlors, nx, ny, nz, hist);
        scan_bins<<<1, 256, 0, stream>>>(hist, offs);
        scatter_kernel<<<(ntot + 255) / 256, 256, 0, stream>>>(
            xlors, ylors, zlors, nx, ny, nz, offs, perm);

        proj_fused<1><<<nb, B, 0, stream>>>(
            img, Px, xlors, ylors, zlors, center, size_, perm, out,
            nx, ny, nz, nbx, nby, G, 0, 0, 0);
    } else {
        proj_fused<0><<<nb, B, 0, stream>>>(
            img, img, xlors, ylors, zlors, center, size_, nullptr, out,
            nx, ny, nz, nbx, nby, G,
            /* x on original: perm (2,0,1) */ 1, G2, G);
    }
}

// Round 6
// 1354.669 us; speedup vs baseline: 1.5281x; 1.5281x over previous
//
#include <hip/hip_runtime.h>
#include <math.h>

// KERNEL_WIDTH = sqrt(9/pi) = 1.6925687506432297
#define KW2_F  2.8647889756541161f   // (9/pi)
#define KW_INV 0.5908179502964271f   // 1/KW
#define RW_F   1.6926f               // slightly >= KW (safe superset bound)

#define NBIN_SET 4096                // 16x16 position x 4x4 slope, per LOR set

__device__ __forceinline__ float fast_sqrtf(float x) {
    return __builtin_amdgcn_sqrtf(x);   // raw v_sqrt_f32, ~1 ulp
}

// ---------------------------------------------------------------------------
// k-chunked (x4, float4) tube-of-response for one LOR. Requires s2 == 1 and
// n2 % 4 == 0. img indexed as jx*s0 + jy*s1 + k.
// Exact superset of the reference 5x5 window taps with w>0 (any w>0 tap has
// |jx-fx| < KW -> |jx-round(fx)| <= 2); w clamped at 0 -> identical sum.
// Inner loop is branch-free: per-row y-interval from the disk equation, then
// unconditional load+fma (compiler pipelines the independent loads).
// ---------------------------------------------------------------------------
__device__ __forceinline__
float tor_lor4(const float* __restrict__ img,
               const float* __restrict__ L,
               float lo0, float lo1, float lo2,
               float vs0, float vs1, float vs2,
               int n0, int n1, int n2, int s0, int s1)
{
    const float inv_vs0 = 1.0f / vs0;
    const float inv_vs1 = 1.0f / vs1;

    const float p1x = L[0], p1y = L[1], p1z = L[2];
    const float p2x = L[3], p2y = L[4], p2z = L[5];
    const float dx = p2x - p1x, dy = p2y - p1y, dz = p2z - p1z;
    const float len = sqrtf(dx * dx + dy * dy + dz * dz);
    const float inv_dz = 1.0f / dz;
    const float step = vs2 * len * fabsf(inv_dz);

    float acc0 = 0.0f, acc1 = 0.0f, acc2 = 0.0f, acc3 = 0.0f;

    for (int k0 = 0; k0 < n2; k0 += 4) {
        float fx[4], fy[4];
#pragma unroll
        for (int j = 0; j < 4; ++j) {
            const float zc = lo2 + ((float)(k0 + j) + 0.5f) * vs2;
            const float t  = (zc - p1z) * inv_dz;
            fx[j] = (fmaf(t, dx, p1x) - lo0) * inv_vs0 - 0.5f;
            fy[j] = (fmaf(t, dy, p1y) - lo1) * inv_vs1 - 0.5f;
        }
        // fx,fy affine in k -> chunk extremes at endpoints.
        const float fxmin = fminf(fx[0], fx[3]), fxmax = fmaxf(fx[0], fx[3]);
        const float fymin = fminf(fy[0], fy[3]), fymax = fmaxf(fy[0], fy[3]);
        const int xlo = max(0,      (int)ceilf (fxmin - RW_F));
        const int xhi = min(n0 - 1, (int)floorf(fxmax + RW_F));

        for (int jx = xlo; jx <= xhi; ++jx) {
            float ddx2[4];
#pragma unroll
            for (int j = 0; j < 4; ++j) {
                const float dxx = (float)jx - fx[j];
                ddx2[j] = dxx * dxx;
            }
            const float rowmin =
                fminf(fminf(ddx2[0], ddx2[1]), fminf(ddx2[2], ddx2[3]));
            if (rowmin >= KW2_F) continue;   // row entirely weightless

            // y-interval covering every j with d2 < KW2 (superset).
            const float rad = fast_sqrtf(KW2_F - rowmin);
            const int ylo = max(0,      (int)ceilf (fymin - rad));
            const int yhi = min(n1 - 1, (int)floorf(fymax + rad));

            const float* rowp = img + jx * s0 + k0;

            for (int jy = ylo; jy <= yhi; ++jy) {
                const float4 v =
                    *reinterpret_cast<const float4*>(rowp + jy * s1);
                float d2[4], wg[4];
#pragma unroll
                for (int j = 0; j < 4; ++j) {
                    const float dyy = (float)jy - fy[j];
                    d2[j] = fmaf(dyy, dyy, ddx2[j]);
                    wg[j] = fmaxf(0.0f, fmaf(-fast_sqrtf(d2[j]), KW_INV, 1.0f));
                }
                acc0 = fmaf(wg[0], v.x, acc0);
                acc1 = fmaf(wg[1], v.y, acc1);
                acc2 = fmaf(wg[2], v.z, acc2);
                acc3 = fmaf(wg[3], v.w, acc3);
            }
        }
    }
    return (acc0 + acc1 + acc2 + acc3) * step;
}

// Scalar guarded fallback (any strides / any n2).
__device__ __forceinline__
float tor_lor_s(const float* __restrict__ img,
                const float* __restrict__ L,
                float lo0, float lo1, float lo2,
                float vs0, float vs1, float vs2,
                int n0, int n1, int n2, int s0, int s1, int s2)
{
    const float inv_vs0 = 1.0f / vs0;
    const float inv_vs1 = 1.0f / vs1;
    const float p1x = L[0], p1y = L[1], p1z = L[2];
    const float p2x = L[3], p2y = L[4], p2z = L[5];
    const float dx = p2x - p1x, dy = p2y - p1y, dz = p2z - p1z;
    const float len = sqrtf(dx * dx + dy * dy + dz * dz);
    const float inv_dz = 1.0f / dz;
    const float step = vs2 * len * fabsf(inv_dz);

    float acc_total = 0.0f;
    for (int k = 0; k < n2; ++k) {
        const float zc = lo2 + ((float)k + 0.5f) * vs2;
        const float t  = (zc - p1z) * inv_dz;
        const float fx = (fmaf(t, dx, p1x) - lo0) * inv_vs0 - 0.5f;
        const float fy = (fmaf(t, dy, p1y) - lo1) * inv_vs1 - 0.5f;
        const int ix = (int)rintf(fx);
        const int iy = (int)rintf(fy);
        const int kb = k * s2;
        float acc = 0.0f;
#pragma unroll
        for (int o0 = -2; o0 <= 2; ++o0) {
            const int jx = ix + o0;
            if ((unsigned)jx >= (unsigned)n0) continue;
            const float dxx  = (float)jx - fx;
            const float ddx2 = dxx * dxx;
            if (ddx2 >= KW2_F) continue;
            const int xb = jx * s0 + kb;
#pragma unroll
            for (int o1 = -2; o1 <= 2; ++o1) {
                const int jy = iy + o1;
                if ((unsigned)jy >= (unsigned)n1) continue;
                const float dyy = (float)jy - fy;
                const float d2  = fmaf(dyy, dyy, ddx2);
                if (d2 < KW2_F) {
                    const float w = fmaf(-fast_sqrtf(d2), KW_INV, 1.0f);
                    acc = fmaf(w, img[xb + jy * s1], acc);
                }
            }
        }
        acc_total += acc;
    }
    return acc_total * step;
}

// ---------------------------------------------------------------------------
// Counting sort, position-major key: 16x16 bins on the transverse midpoint
// (locality: a wave's lanes share a ~7.5-voxel patch) x 4x4 bins on signed
// slope (trip-count convergence). LOR layout: (t0,t1,-H, u0,u1,+H) in every
// set's own frame, so L[0],L[1]/L[3],L[4] are the transverse coordinates.
// ---------------------------------------------------------------------------
__device__ __forceinline__ int lor_key(const float* __restrict__ L)
{
    const float m0 = 0.5f * (L[0] + L[3]);
    const float m1 = 0.5f * (L[1] + L[4]);
    const float invdz = 1.0f / (L[5] - L[2]);
    const float sl0 = (L[3] - L[0]) * invdz;
    const float sl1 = (L[4] - L[1]) * invdz;
    const int qp0 = min(15, max(0, (int)((m0 + 60.0f) * 0.13333334f)));
    const int qp1 = min(15, max(0, (int)((m1 + 60.0f) * 0.13333334f)));
    const int qs0 = min(3,  max(0, (int)((sl0 + 0.75f) * 2.6666667f)));
    const int qs1 = min(3,  max(0, (int)((sl1 + 0.75f) * 2.6666667f)));
    return (((qp0 << 4) | qp1) << 4) | (qs0 << 2) | qs1;
}

__global__ __launch_bounds__(256)
void zero_bins(unsigned* __restrict__ bins, int n)
{
    const int t = blockIdx.x * 256 + threadIdx.x;
    if (t < n) bins[t] = 0u;
}

__global__ __launch_bounds__(256)
void hist_kernel(const float* __restrict__ xl, const float* __restrict__ yl,
                 const float* __restrict__ zl,
                 int nx, int ny, int nz, unsigned* __restrict__ hist)
{
    const int t = blockIdx.x * 256 + threadIdx.x;
    const float* L; int set;
    if (t < nx)                { L = xl + 6 * (size_t)t;              set = 0; }
    else if (t < nx + ny)      { L = yl + 6 * (size_t)(t - nx);       set = 1; }
    else if (t < nx + ny + nz) { L = zl + 6 * (size_t)(t - nx - ny);  set = 2; }
    else return;
    atomicAdd(&hist[set * NBIN_SET + lor_key(L)], 1u);
}

// Exclusive scan of each set's 4096 bins. One block per set.
__global__ __launch_bounds__(256)
void scan_bins(const unsigned* __restrict__ hist, unsigned* __restrict__ offs)
{
    __shared__ unsigned part[256];
    const int set = blockIdx.x;
    const unsigned* h = hist + set * NBIN_SET;
    unsigned* o = offs + set * NBIN_SET;
    const int t = threadIdx.x;

    unsigned loc[16];
    unsigned run = 0;
#pragma unroll
    for (int k = 0; k < 16; ++k) { loc[k] = run; run += h[t * 16 + k]; }
    part[t] = run;
    __syncthreads();
    for (int off = 1; off < 256; off <<= 1) {
        const unsigned v = (t >= off) ? part[t - off] : 0u;
        __syncthreads();
        part[t] += v;
        __syncthreads();
    }
    const unsigned base = (t == 0) ? 0u : part[t - 1];
#pragma unroll
    for (int k = 0; k < 16; ++k) o[t * 16 + k] = base + loc[k];
}

__global__ __launch_bounds__(256)
void scatter_kernel(const float* __restrict__ xl, const float* __restrict__ yl,
                    const float* __restrict__ zl,
                    int nx, int ny, int nz,
                    unsigned* __restrict__ offs, unsigned* __restrict__ perm)
{
    const int t = blockIdx.x * 256 + threadIdx.x;
    const float* L; int set, i, base;
    if (t < nx)                { L = xl + 6 * (size_t)t;             set = 0; i = t;            base = 0;       }
    else if (t < nx + ny)      { L = yl + 6 * (size_t)(t - nx);      set = 1; i = t - nx;       base = nx;      }
    else if (t < nx + ny + nz) { L = zl + 6 * (size_t)(t - nx - ny); set = 2; i = t - nx - ny;  base = nx + ny; }
    else return;
    const unsigned pos = atomicAdd(&offs[set * NBIN_SET + lor_key(L)], 1u);
    perm[base + pos] = (unsigned)i;
}

// ---------------------------------------------------------------------------
// Fused launch: block ranges pick the LOR set. FOUR==1 -> float4 path with
// sorted perm indirection (s2==1 for all sets; x uses transposed copy).
// ---------------------------------------------------------------------------
template<int FOUR>
__global__ __launch_bounds__(128)
void proj_fused(const float* __restrict__ imgZ,
                const float* __restrict__ imgX,
                const float* __restrict__ xlors,
                const float* __restrict__ ylors,
                const float* __restrict__ zlors,
                const float* __restrict__ center,
                const float* __restrict__ size_,
                const unsigned* __restrict__ perm,
                float* __restrict__ out,
                int nx, int ny, int nz,
                int nbx, int nby, int G,
                int xs0, int xs1, int xs2)  // x-set strides (scalar path)
{
    const int b = blockIdx.x;
    const int G2 = G * G;

    const float* img;
    const float* lors;
    float* op;
    int a0, a1, a2, s0, s1, s2;

    if (b < nbx) {            // px: perm (2,0,1)
        const int idx = b * 128 + threadIdx.x;
        if (idx >= nx) return;
        const int i = FOUR ? (int)perm[idx] : idx;
        img = FOUR ? imgX : imgZ;
        lors = xlors + 6 * (size_t)i;  op = out + i;
        a0 = 2; a1 = 0; a2 = 1;
        if (FOUR) { s0 = G2; s1 = G; s2 = 1; }
        else      { s0 = xs0; s1 = xs1; s2 = xs2; }
    } else if (b < nbx + nby) {  // py: perm (1,0,2)
        const int idx = (b - nbx) * 128 + threadIdx.x;
        if (idx >= ny) return;
        const int i = FOUR ? (int)perm[nx + idx] : idx;
        img = imgZ; lors = ylors + 6 * (size_t)i;  op = out + nx + i;
        a0 = 1; a1 = 0; a2 = 2;  s0 = G; s1 = G2; s2 = 1;
    } else {                     // pz: identity
        const int idx = (b - nbx - nby) * 128 + threadIdx.x;
        if (idx >= nz) return;
        const int i = FOUR ? (int)perm[nx + ny + idx] : idx;
        img = imgZ; lors = zlors + 6 * (size_t)i;  op = out + nx + ny + i;
        a0 = 0; a1 = 1; a2 = 2;  s0 = G2; s1 = G; s2 = 1;
    }

    const float S0 = size_[a0], S1 = size_[a1], S2 = size_[a2];
    const float vs0 = S0 / (float)G, vs1 = S1 / (float)G, vs2 = S2 / (float)G;
    const float lo0 = center[a0] - 0.5f * S0;
    const float lo1 = center[a1] - 0.5f * S1;
    const float lo2 = center[a2] - 0.5f * S2;

    float r;
    if (FOUR)
        r = tor_lor4(img, lors, lo0, lo1, lo2, vs0, vs1, vs2,
                     G, G, G, s0, s1);
    else
        r = tor_lor_s(img, lors, lo0, lo1, lo2, vs0, vs1, vs2,
                      G, G, G, s0, s1, s2);
    *op = r;
}

// 2D transpose in[R][C] -> out[C][R]; Px[c,i0,i1] = image[i0,i1,c]
// giving the x-perm with strides (G^2, G, 1). R, C divisible by 32.
__global__ __launch_bounds__(256)
void transpose_RC(const float* __restrict__ in, float* __restrict__ outp,
                  int R, int C)
{
    __shared__ float tile[32][33];
    const int rt = blockIdx.x * 32;
    const int ct = blockIdx.y * 32;
    const int tx = threadIdx.x;
    const int ty = threadIdx.y;   // block (32,8)
#pragma unroll
    for (int j = 0; j < 32; j += 8)
        tile[ty + j][tx] = in[(size_t)(rt + ty + j) * C + (ct + tx)];
    __syncthreads();
#pragma unroll
    for (int j = 0; j < 32; j += 8)
        outp[(size_t)(ct + ty + j) * R + (rt + tx)] = tile[tx][ty + j];
}

extern "C" void kernel_launch(void* const* d_in, const int* in_sizes, int n_in,
                              void* d_out, int out_size, void* d_ws, size_t ws_size,
                              hipStream_t stream)
{
    const float* img    = (const float*)d_in[0];
    const float* center = (const float*)d_in[2];
    const float* size_  = (const float*)d_in[3];
    const float* xlors  = (const float*)d_in[4];
    const float* ylors  = (const float*)d_in[5];
    const float* zlors  = (const float*)d_in[6];
    float* out = (float*)d_out;

    const int nx = in_sizes[4] / 6;
    const int ny = in_sizes[5] / 6;
    const int nz = in_sizes[6] / 6;
    const int ntot = nx + ny + nz;

    int G = (int)lround(cbrt((double)in_sizes[0]));
    const int G2 = G * G;

    const int B = 128;
    const int nbx = (nx + B - 1) / B;
    const int nby = (ny + B - 1) / B;
    const int nbz = (nz + B - 1) / B;
    const int nb  = nbx + nby + nbz;

    // Workspace: [Px: G^3 f32][hist: 3*4096 u32][offs: 3*4096 u32][perm: ntot u32]
    const size_t pxBytes   = (size_t)G * G2 * sizeof(float);
    const int    nbins     = 3 * NBIN_SET;
    const size_t needBytes = pxBytes + 2 * (size_t)nbins * sizeof(unsigned)
                           + (size_t)ntot * sizeof(unsigned);
    const bool fast = (G % 32 == 0) && (ws_size >= needBytes);

    if (fast) {
        float*    Px   = (float*)d_ws;
        unsigned* hist = (unsigned*)((char*)d_ws + pxBytes);
        unsigned* offs = hist + nbins;
        unsigned* perm = offs + nbins;

        transpose_RC<<<dim3(G2 / 32, G / 32), dim3(32, 8), 0, stream>>>(
            img, Px, G2, G);

        zero_bins<<<(nbins + 255) / 256, 256, 0, stream>>>(hist, nbins);
        hist_kernel<<<(ntot + 255) / 256, 256, 0, stream>>>(
            xlors, ylors, zlors, nx, ny, nz, hist);
        scan_bins<<<3, 256, 0, stream>>>(hist, offs);
        scatter_kernel<<<(ntot + 255) / 256, 256, 0, stream>>>(
            xlors, ylors, zlors, nx, ny, nz, offs, perm);

        proj_fused<1><<<nb, B, 0, stream>>>(
            img, Px, xlors, ylors, zlors, center, size_, perm, out,
            nx, ny, nz, nbx, nby, G, 0, 0, 0);
    } else {
        proj_fused<0><<<nb, B, 0, stream>>>(
            img, img, xlors, ylors, zlors, center, size_, nullptr, out,
            nx, ny, nz, nbx, nby, G,
            /* x on original: perm (2,0,1) */ 1, G2, G);
    }
}

// Round 7
// 1264.611 us; speedup vs baseline: 1.6369x; 1.0712x over previous
//
#include <hip/hip_runtime.h>
#include <math.h>

// KERNEL_WIDTH = sqrt(9/pi) = 1.6925687506432297
#define KW2_F  2.8647889756541161f   // (9/pi)
#define KW_INV 0.5908179502964271f   // 1/KW
#define RW_F   1.6926f               // slightly >= KW (safe superset bound)

// Sort key: slope-MAJOR (8x8), position-minor (16x16) -> 16384 bins per set.
// Wave of 64 then shares one slope bin (uniform trip counts) and a run of
// adjacent position bins (cache locality).
#define NBIN_SET 16384

__device__ __forceinline__ float fast_sqrtf(float x) {
    return __builtin_amdgcn_sqrtf(x);   // raw v_sqrt_f32, ~1 ulp
}

// ---------------------------------------------------------------------------
// k-chunked (x4, float4) tube-of-response for one LOR. Requires s2 == 1 and
// n2 % 4 == 0. img indexed as jx*s0 + jy*s1 + k.
// Exact superset of reference taps with w>0 (w>0 => |jx-fx|<KW =>
// |jx-round(fx)|<=2, inside the 5x5 window); w clamps at 0 -> identical sum.
// Branch-free rows: rowmin>=KW2 is impossible up to boundary rounding given
// xlo/xhi (rows within RW of the segment), so rad just clamps at 0.
// jy unrolled x2: two independent float4 loads in flight per iteration.
// ---------------------------------------------------------------------------
__device__ __forceinline__
float tor_lor4(const float* __restrict__ img,
               const float* __restrict__ L,
               float lo0, float lo1, float lo2,
               float vs0, float vs1, float vs2,
               int n0, int n1, int n2, int s0, int s1)
{
    const float inv_vs0 = 1.0f / vs0;
    const float inv_vs1 = 1.0f / vs1;

    const float p1x = L[0], p1y = L[1], p1z = L[2];
    const float p2x = L[3], p2y = L[4], p2z = L[5];
    const float dx = p2x - p1x, dy = p2y - p1y, dz = p2z - p1z;
    const float len = sqrtf(dx * dx + dy * dy + dz * dz);
    const float inv_dz = 1.0f / dz;
    const float step = vs2 * len * fabsf(inv_dz);

    // fx/fy are affine in k: initialize k=0..3, then increment by 4*slope.
    float fx[4], fy[4];
#pragma unroll
    for (int j = 0; j < 4; ++j) {
        const float zc = lo2 + ((float)j + 0.5f) * vs2;
        const float t  = (zc - p1z) * inv_dz;
        fx[j] = (fmaf(t, dx, p1x) - lo0) * inv_vs0 - 0.5f;
        fy[j] = (fmaf(t, dy, p1y) - lo1) * inv_vs1 - 0.5f;
    }
    const float dfx4 = 4.0f * vs2 * inv_dz * dx * inv_vs0;
    const float dfy4 = 4.0f * vs2 * inv_dz * dy * inv_vs1;

    float acc0 = 0.0f, acc1 = 0.0f, acc2 = 0.0f, acc3 = 0.0f;

    for (int k0 = 0; k0 < n2; k0 += 4) {
        const float fxmin = fminf(fx[0], fx[3]), fxmax = fmaxf(fx[0], fx[3]);
        const float fymin = fminf(fy[0], fy[3]), fymax = fmaxf(fy[0], fy[3]);
        const int xlo = max(0,      (int)ceilf (fxmin - RW_F));
        const int xhi = min(n0 - 1, (int)floorf(fxmax + RW_F));

        const float* rowp = img + xlo * s0 + k0;

        for (int jx = xlo; jx <= xhi; ++jx, rowp += s0) {
            float ddx2[4];
#pragma unroll
            for (int j = 0; j < 4; ++j) {
                const float dxx = (float)jx - fx[j];
                ddx2[j] = dxx * dxx;
            }
            const float rowmin =
                fminf(fminf(ddx2[0], ddx2[1]), fminf(ddx2[2], ddx2[3]));
            const float rad = fast_sqrtf(fmaxf(KW2_F - rowmin, 0.0f));
            const int ylo = max(0,      (int)ceilf (fymin - rad));
            const int yhi = min(n1 - 1, (int)floorf(fymax + rad));

            const float* p = rowp + ylo * s1;
            int jy = ylo;
            // pairs: two independent float4 loads per iteration
            for (; jy + 1 <= yhi; jy += 2, p += 2 * s1) {
                const float4 va = *reinterpret_cast<const float4*>(p);
                const float4 vb = *reinterpret_cast<const float4*>(p + s1);
                float wa[4], wb[4];
#pragma unroll
                for (int j = 0; j < 4; ++j) {
                    const float da = (float)jy - fy[j];
                    const float db = (float)(jy + 1) - fy[j];
                    const float d2a = fmaf(da, da, ddx2[j]);
                    const float d2b = fmaf(db, db, ddx2[j]);
                    wa[j] = fmaxf(0.0f, fmaf(-fast_sqrtf(d2a), KW_INV, 1.0f));
                    wb[j] = fmaxf(0.0f, fmaf(-fast_sqrtf(d2b), KW_INV, 1.0f));
                }
                acc0 = fmaf(wa[0], va.x, acc0);
                acc1 = fmaf(wa[1], va.y, acc1);
                acc2 = fmaf(wa[2], va.z, acc2);
                acc3 = fmaf(wa[3], va.w, acc3);
                acc0 = fmaf(wb[0], vb.x, acc0);
                acc1 = fmaf(wb[1], vb.y, acc1);
                acc2 = fmaf(wb[2], vb.z, acc2);
                acc3 = fmaf(wb[3], vb.w, acc3);
            }
            if (jy <= yhi) {
                const float4 v = *reinterpret_cast<const float4*>(p);
                float wg[4];
#pragma unroll
                for (int j = 0; j < 4; ++j) {
                    const float dyy = (float)jy - fy[j];
                    const float d2  = fmaf(dyy, dyy, ddx2[j]);
                    wg[j] = fmaxf(0.0f, fmaf(-fast_sqrtf(d2), KW_INV, 1.0f));
                }
                acc0 = fmaf(wg[0], v.x, acc0);
                acc1 = fmaf(wg[1], v.y, acc1);
                acc2 = fmaf(wg[2], v.z, acc2);
                acc3 = fmaf(wg[3], v.w, acc3);
            }
        }
#pragma unroll
        for (int j = 0; j < 4; ++j) { fx[j] += dfx4; fy[j] += dfy4; }
    }
    return (acc0 + acc1 + acc2 + acc3) * step;
}

// Scalar guarded fallback (any strides / any n2).
__device__ __forceinline__
float tor_lor_s(const float* __restrict__ img,
                const float* __restrict__ L,
                float lo0, float lo1, float lo2,
                float vs0, float vs1, float vs2,
                int n0, int n1, int n2, int s0, int s1, int s2)
{
    const float inv_vs0 = 1.0f / vs0;
    const float inv_vs1 = 1.0f / vs1;
    const float p1x = L[0], p1y = L[1], p1z = L[2];
    const float p2x = L[3], p2y = L[4], p2z = L[5];
    const float dx = p2x - p1x, dy = p2y - p1y, dz = p2z - p1z;
    const float len = sqrtf(dx * dx + dy * dy + dz * dz);
    const float inv_dz = 1.0f / dz;
    const float step = vs2 * len * fabsf(inv_dz);

    float acc_total = 0.0f;
    for (int k = 0; k < n2; ++k) {
        const float zc = lo2 + ((float)k + 0.5f) * vs2;
        const float t  = (zc - p1z) * inv_dz;
        const float fx = (fmaf(t, dx, p1x) - lo0) * inv_vs0 - 0.5f;
        const float fy = (fmaf(t, dy, p1y) - lo1) * inv_vs1 - 0.5f;
        const int ix = (int)rintf(fx);
        const int iy = (int)rintf(fy);
        const int kb = k * s2;
        float acc = 0.0f;
#pragma unroll
        for (int o0 = -2; o0 <= 2; ++o0) {
            const int jx = ix + o0;
            if ((unsigned)jx >= (unsigned)n0) continue;
            const float dxx  = (float)jx - fx;
            const float ddx2 = dxx * dxx;
            if (ddx2 >= KW2_F) continue;
            const int xb = jx * s0 + kb;
#pragma unroll
            for (int o1 = -2; o1 <= 2; ++o1) {
                const int jy = iy + o1;
                if ((unsigned)jy >= (unsigned)n1) continue;
                const float dyy = (float)jy - fy;
                const float d2  = fmaf(dyy, dyy, ddx2);
                if (d2 < KW2_F) {
                    const float w = fmaf(-fast_sqrtf(d2), KW_INV, 1.0f);
                    acc = fmaf(w, img[xb + jy * s1], acc);
                }
            }
        }
        acc_total += acc;
    }
    return acc_total * step;
}

// ---------------------------------------------------------------------------
// Counting sort. Key: slope-major 8x8 (trip-count convergence within a wave),
// position-minor 16x16 on transverse midpoint (locality). LOR layout is
// (t0,t1,-H, u0,u1,+H), so L[0],L[1]/L[3],L[4] are transverse coords.
// ---------------------------------------------------------------------------
__device__ __forceinline__ int lor_key(const float* __restrict__ L)
{
    const float m0 = 0.5f * (L[0] + L[3]);
    const float m1 = 0.5f * (L[1] + L[4]);
    const float invdz = 1.0f / (L[5] - L[2]);
    const float sl0 = (L[3] - L[0]) * invdz;
    const float sl1 = (L[4] - L[1]) * invdz;
    const int qp0 = min(15, max(0, (int)((m0 + 60.0f) * 0.13333334f)));
    const int qp1 = min(15, max(0, (int)((m1 + 60.0f) * 0.13333334f)));
    const int qs0 = min(7,  max(0, (int)((sl0 + 0.75f) * 5.3333335f)));
    const int qs1 = min(7,  max(0, (int)((sl1 + 0.75f) * 5.3333335f)));
    return (((qs0 << 3) | qs1) << 8) | (qp0 << 4) | qp1;
}

__global__ __launch_bounds__(256)
void zero_bins(unsigned* __restrict__ bins, int n)
{
    const int t = blockIdx.x * 256 + threadIdx.x;
    if (t < n) bins[t] = 0u;
}

__global__ __launch_bounds__(256)
void hist_kernel(const float* __restrict__ xl, const float* __restrict__ yl,
                 const float* __restrict__ zl,
                 int nx, int ny, int nz, unsigned* __restrict__ hist)
{
    const int t = blockIdx.x * 256 + threadIdx.x;
    const float* L; int set;
    if (t < nx)                { L = xl + 6 * (size_t)t;              set = 0; }
    else if (t < nx + ny)      { L = yl + 6 * (size_t)(t - nx);       set = 1; }
    else if (t < nx + ny + nz) { L = zl + 6 * (size_t)(t - nx - ny);  set = 2; }
    else return;
    atomicAdd(&hist[set * NBIN_SET + lor_key(L)], 1u);
}

// Exclusive scan of each set's 16384 bins. One 1024-thread block per set.
__global__ __launch_bounds__(1024)
void scan_bins(const unsigned* __restrict__ hist, unsigned* __restrict__ offs)
{
    __shared__ unsigned part[1024];
    const int set = blockIdx.x;
    const unsigned* h = hist + set * NBIN_SET;
    unsigned* o = offs + set * NBIN_SET;
    const int t = threadIdx.x;

    unsigned loc[16];
    unsigned run = 0;
#pragma unroll
    for (int k = 0; k < 16; ++k) { loc[k] = run; run += h[t * 16 + k]; }
    part[t] = run;
    __syncthreads();
    for (int off = 1; off < 1024; off <<= 1) {
        const unsigned v = (t >= off) ? part[t - off] : 0u;
        __syncthreads();
        part[t] += v;
        __syncthreads();
    }
    const unsigned base = (t == 0) ? 0u : part[t - 1];
#pragma unroll
    for (int k = 0; k < 16; ++k) o[t * 16 + k] = base + loc[k];
}

__global__ __launch_bounds__(256)
void scatter_kernel(const float* __restrict__ xl, const float* __restrict__ yl,
                    const float* __restrict__ zl,
                    int nx, int ny, int nz,
                    unsigned* __restrict__ offs, unsigned* __restrict__ perm)
{
    const int t = blockIdx.x * 256 + threadIdx.x;
    const float* L; int set, i, base;
    if (t < nx)                { L = xl + 6 * (size_t)t;             set = 0; i = t;            base = 0;       }
    else if (t < nx + ny)      { L = yl + 6 * (size_t)(t - nx);      set = 1; i = t - nx;       base = nx;      }
    else if (t < nx + ny + nz) { L = zl + 6 * (size_t)(t - nx - ny); set = 2; i = t - nx - ny;  base = nx + ny; }
    else return;
    const unsigned pos = atomicAdd(&offs[set * NBIN_SET + lor_key(L)], 1u);
    perm[base + pos] = (unsigned)i;
}

// ---------------------------------------------------------------------------
// Fused launch: block ranges pick the LOR set. FOUR==1 -> float4 path with
// sorted perm indirection (s2==1 for all sets; x uses transposed copy).
// ---------------------------------------------------------------------------
template<int FOUR>
__global__ __launch_bounds__(256)
void proj_fused(const float* __restrict__ imgZ,
                const float* __restrict__ imgX,
                const float* __restrict__ xlors,
                const float* __restrict__ ylors,
                const float* __restrict__ zlors,
                const float* __restrict__ center,
                const float* __restrict__ size_,
                const unsigned* __restrict__ perm,
                float* __restrict__ out,
                int nx, int ny, int nz,
                int nbx, int nby, int G,
                int xs0, int xs1, int xs2)  // x-set strides (scalar path)
{
    const int b = blockIdx.x;
    const int G2 = G * G;

    const float* img;
    const float* lors;
    float* op;
    int a0, a1, a2, s0, s1, s2;

    if (b < nbx) {            // px: perm (2,0,1)
        const int idx = b * 256 + threadIdx.x;
        if (idx >= nx) return;
        const int i = FOUR ? (int)perm[idx] : idx;
        img = FOUR ? imgX : imgZ;
        lors = xlors + 6 * (size_t)i;  op = out + i;
        a0 = 2; a1 = 0; a2 = 1;
        if (FOUR) { s0 = G2; s1 = G; s2 = 1; }
        else      { s0 = xs0; s1 = xs1; s2 = xs2; }
    } else if (b < nbx + nby) {  // py: perm (1,0,2)
        const int idx = (b - nbx) * 256 + threadIdx.x;
        if (idx >= ny) return;
        const int i = FOUR ? (int)perm[nx + idx] : idx;
        img = imgZ; lors = ylors + 6 * (size_t)i;  op = out + nx + i;
        a0 = 1; a1 = 0; a2 = 2;  s0 = G; s1 = G2; s2 = 1;
    } else {                     // pz: identity
        const int idx = (b - nbx - nby) * 256 + threadIdx.x;
        if (idx >= nz) return;
        const int i = FOUR ? (int)perm[nx + ny + idx] : idx;
        img = imgZ; lors = zlors + 6 * (size_t)i;  op = out + nx + ny + i;
        a0 = 0; a1 = 1; a2 = 2;  s0 = G2; s1 = G; s2 = 1;
    }

    const float S0 = size_[a0], S1 = size_[a1], S2 = size_[a2];
    const float vs0 = S0 / (float)G, vs1 = S1 / (float)G, vs2 = S2 / (float)G;
    const float lo0 = center[a0] - 0.5f * S0;
    const float lo1 = center[a1] - 0.5f * S1;
    const float lo2 = center[a2] - 0.5f * S2;

    float r;
    if (FOUR)
        r = tor_lor4(img, lors, lo0, lo1, lo2, vs0, vs1, vs2,
                     G, G, G, s0, s1);
    else
        r = tor_lor_s(img, lors, lo0, lo1, lo2, vs0, vs1, vs2,
                      G, G, G, s0, s1, s2);
    *op = r;
}

// 2D transpose in[R][C] -> out[C][R]; Px[c,i0,i1] = image[i0,i1,c]
// giving the x-perm with strides (G^2, G, 1). R, C divisible by 32.
__global__ __launch_bounds__(256)
void transpose_RC(const float* __restrict__ in, float* __restrict__ outp,
                  int R, int C)
{
    __shared__ float tile[32][33];
    const int rt = blockIdx.x * 32;
    const int ct = blockIdx.y * 32;
    const int tx = threadIdx.x;
    const int ty = threadIdx.y;   // block (32,8)
#pragma unroll
    for (int j = 0; j < 32; j += 8)
        tile[ty + j][tx] = in[(size_t)(rt + ty + j) * C + (ct + tx)];
    __syncthreads();
#pragma unroll
    for (int j = 0; j < 32; j += 8)
        outp[(size_t)(ct + ty + j) * R + (rt + tx)] = tile[tx][ty + j];
}

extern "C" void kernel_launch(void* const* d_in, const int* in_sizes, int n_in,
                              void* d_out, int out_size, void* d_ws, size_t ws_size,
                              hipStream_t stream)
{
    const float* img    = (const float*)d_in[0];
    const float* center = (const float*)d_in[2];
    const float* size_  = (const float*)d_in[3];
    const float* xlors  = (const float*)d_in[4];
    const float* ylors  = (const float*)d_in[5];
    const float* zlors  = (const float*)d_in[6];
    float* out = (float*)d_out;

    const int nx = in_sizes[4] / 6;
    const int ny = in_sizes[5] / 6;
    const int nz = in_sizes[6] / 6;
    const int ntot = nx + ny + nz;

    int G = (int)lround(cbrt((double)in_sizes[0]));
    const int G2 = G * G;

    const int B = 256;
    const int nbx = (nx + B - 1) / B;
    const int nby = (ny + B - 1) / B;
    const int nbz = (nz + B - 1) / B;
    const int nb  = nbx + nby + nbz;

    // Workspace: [Px: G^3 f32][hist: 3*16384 u32][offs: 3*16384 u32][perm: ntot u32]
    const size_t pxBytes   = (size_t)G * G2 * sizeof(float);
    const int    nbins     = 3 * NBIN_SET;
    const size_t needBytes = pxBytes + 2 * (size_t)nbins * sizeof(unsigned)
                           + (size_t)ntot * sizeof(unsigned);
    const bool fast = (G % 32 == 0) && (ws_size >= needBytes);

    if (fast) {
        float*    Px   = (float*)d_ws;
        unsigned* hist = (unsigned*)((char*)d_ws + pxBytes);
        unsigned* offs = hist + nbins;
        unsigned* perm = offs + nbins;

        transpose_RC<<<dim3(G2 / 32, G / 32), dim3(32, 8), 0, stream>>>(
            img, Px, G2, G);

        zero_bins<<<(nbins + 255) / 256, 256, 0, stream>>>(hist, nbins);
        hist_kernel<<<(ntot + 255) / 256, 256, 0, stream>>>(
            xlors, ylors, zlors, nx, ny, nz, hist);
        scan_bins<<<3, 1024, 0, stream>>>(hist, offs);
        scatter_kernel<<<(ntot + 255) / 256, 256, 0, stream>>>(
            xlors, ylors, zlors, nx, ny, nz, offs, perm);

        proj_fused<1><<<nb, B, 0, stream>>>(
            img, Px, xlors, ylors, zlors, center, size_, perm, out,
            nx, ny, nz, nbx, nby, G, 0, 0, 0);
    } else {
        proj_fused<0><<<nb, B, 0, stream>>>(
            img, img, xlors, ylors, zlors, center, size_, nullptr, out,
            nx, ny, nz, nbx, nby, G,
            /* x on original: perm (2,0,1) */ 1, G2, G);
    }
}

// Round 8
// 1178.863 us; speedup vs baseline: 1.7559x; 1.0727x over previous
//
#include <hip/hip_runtime.h>
#include <math.h>

// KERNEL_WIDTH = sqrt(9/pi) = 1.6925687506432297
#define KW2_F  2.8647889756541161f   // (9/pi)
#define KW_INV 0.5908179502964271f   // 1/KW
#define RW_F   1.6926f               // slightly >= KW (safe superset bound)

// Sort key: slope-major 8x8, position-minor 16x16 -> 16384 bins per set.
#define NBIN_SET 16384

__device__ __forceinline__ float fast_sqrtf(float x) {
    return __builtin_amdgcn_sqrtf(x);   // raw v_sqrt_f32, ~1 ulp
}

// ---------------------------------------------------------------------------
// Cooperative tube-of-response: 32 lanes per LOR, lane c owns k-chunk
// [4c, 4c+4). Requires s2 == 1, n2 % 4 == 0, n2/4 <= 32*loop. Lanes of one
// LOR load from adjacent k for near-identical rows -> wave-loads touch few
// distinct cache lines; trip counts are uniform across lanes (same slope).
// Exact superset of reference taps with w>0 (w>0 => |jx-fx| < KW =>
// |jx-round(fx)| <= 2 inside the 5x5 window); w clamps at 0.
// Returns the lane's partial sum (un-stepped).
// ---------------------------------------------------------------------------
__device__ __forceinline__
float tor_chunk(const float* __restrict__ img,
                float fx0, float fy0, float dfx, float dfy, // value at k=0.5 voxel, per-k slope
                int k0,
                int n0, int n1, int s0, int s1)
{
    float fx[4], fy[4];
#pragma unroll
    for (int j = 0; j < 4; ++j) {
        fx[j] = fmaf((float)(k0 + j), dfx, fx0);
        fy[j] = fmaf((float)(k0 + j), dfy, fy0);
    }
    const float fxmin = fminf(fx[0], fx[3]), fxmax = fmaxf(fx[0], fx[3]);
    const float fymin = fminf(fy[0], fy[3]), fymax = fmaxf(fy[0], fy[3]);
    const int xlo = max(0,      (int)ceilf (fxmin - RW_F));
    const int xhi = min(n0 - 1, (int)floorf(fxmax + RW_F));

    float acc0 = 0.0f, acc1 = 0.0f, acc2 = 0.0f, acc3 = 0.0f;

    const float* rowp = img + xlo * s0 + k0;
    for (int jx = xlo; jx <= xhi; ++jx, rowp += s0) {
        float ddx2[4];
#pragma unroll
        for (int j = 0; j < 4; ++j) {
            const float dxx = (float)jx - fx[j];
            ddx2[j] = dxx * dxx;
        }
        const float rowmin =
            fminf(fminf(ddx2[0], ddx2[1]), fminf(ddx2[2], ddx2[3]));
        const float rad = fast_sqrtf(fmaxf(KW2_F - rowmin, 0.0f));
        const int ylo = max(0,      (int)ceilf (fymin - rad));
        const int yhi = min(n1 - 1, (int)floorf(fymax + rad));

        const float* p = rowp + ylo * s1;
        int jy = ylo;
        for (; jy + 1 <= yhi; jy += 2, p += 2 * s1) {
            const float4 va = *reinterpret_cast<const float4*>(p);
            const float4 vb = *reinterpret_cast<const float4*>(p + s1);
            float wa[4], wb[4];
#pragma unroll
            for (int j = 0; j < 4; ++j) {
                const float da = (float)jy - fy[j];
                const float db = (float)(jy + 1) - fy[j];
                const float d2a = fmaf(da, da, ddx2[j]);
                const float d2b = fmaf(db, db, ddx2[j]);
                wa[j] = fmaxf(0.0f, fmaf(-fast_sqrtf(d2a), KW_INV, 1.0f));
                wb[j] = fmaxf(0.0f, fmaf(-fast_sqrtf(d2b), KW_INV, 1.0f));
            }
            acc0 = fmaf(wa[0], va.x, acc0);
            acc1 = fmaf(wa[1], va.y, acc1);
            acc2 = fmaf(wa[2], va.z, acc2);
            acc3 = fmaf(wa[3], va.w, acc3);
            acc0 = fmaf(wb[0], vb.x, acc0);
            acc1 = fmaf(wb[1], vb.y, acc1);
            acc2 = fmaf(wb[2], vb.z, acc2);
            acc3 = fmaf(wb[3], vb.w, acc3);
        }
        if (jy <= yhi) {
            const float4 v = *reinterpret_cast<const float4*>(p);
            float wg[4];
#pragma unroll
            for (int j = 0; j < 4; ++j) {
                const float dyy = (float)jy - fy[j];
                const float d2  = fmaf(dyy, dyy, ddx2[j]);
                wg[j] = fmaxf(0.0f, fmaf(-fast_sqrtf(d2), KW_INV, 1.0f));
            }
            acc0 = fmaf(wg[0], v.x, acc0);
            acc1 = fmaf(wg[1], v.y, acc1);
            acc2 = fmaf(wg[2], v.z, acc2);
            acc3 = fmaf(wg[3], v.w, acc3);
        }
    }
    return (acc0 + acc1) + (acc2 + acc3);
}

// Scalar guarded fallback (any strides / any n2), one thread per LOR.
__device__ __forceinline__
float tor_lor_s(const float* __restrict__ img,
                const float* __restrict__ L,
                float lo0, float lo1, float lo2,
                float vs0, float vs1, float vs2,
                int n0, int n1, int n2, int s0, int s1, int s2)
{
    const float inv_vs0 = 1.0f / vs0;
    const float inv_vs1 = 1.0f / vs1;
    const float p1x = L[0], p1y = L[1], p1z = L[2];
    const float p2x = L[3], p2y = L[4], p2z = L[5];
    const float dx = p2x - p1x, dy = p2y - p1y, dz = p2z - p1z;
    const float len = sqrtf(dx * dx + dy * dy + dz * dz);
    const float inv_dz = 1.0f / dz;
    const float step = vs2 * len * fabsf(inv_dz);

    float acc_total = 0.0f;
    for (int k = 0; k < n2; ++k) {
        const float zc = lo2 + ((float)k + 0.5f) * vs2;
        const float t  = (zc - p1z) * inv_dz;
        const float fx = (fmaf(t, dx, p1x) - lo0) * inv_vs0 - 0.5f;
        const float fy = (fmaf(t, dy, p1y) - lo1) * inv_vs1 - 0.5f;
        const int ix = (int)rintf(fx);
        const int iy = (int)rintf(fy);
        const int kb = k * s2;
        float acc = 0.0f;
#pragma unroll
        for (int o0 = -2; o0 <= 2; ++o0) {
            const int jx = ix + o0;
            if ((unsigned)jx >= (unsigned)n0) continue;
            const float dxx  = (float)jx - fx;
            const float ddx2 = dxx * dxx;
            if (ddx2 >= KW2_F) continue;
            const int xb = jx * s0 + kb;
#pragma unroll
            for (int o1 = -2; o1 <= 2; ++o1) {
                const int jy = iy + o1;
                if ((unsigned)jy >= (unsigned)n1) continue;
                const float dyy = (float)jy - fy;
                const float d2  = fmaf(dyy, dyy, ddx2);
                if (d2 < KW2_F) {
                    const float w = fmaf(-fast_sqrtf(d2), KW_INV, 1.0f);
                    acc = fmaf(w, img[xb + jy * s1], acc);
                }
            }
        }
        acc_total += acc;
    }
    return acc_total * step;
}

// ---------------------------------------------------------------------------
// Counting sort. Key: slope-major 8x8 (wave pairs get similar trip counts),
// position-minor 16x16 on transverse midpoint (L2 locality).
// ---------------------------------------------------------------------------
__device__ __forceinline__ int lor_key(const float* __restrict__ L)
{
    const float m0 = 0.5f * (L[0] + L[3]);
    const float m1 = 0.5f * (L[1] + L[4]);
    const float invdz = 1.0f / (L[5] - L[2]);
    const float sl0 = (L[3] - L[0]) * invdz;
    const float sl1 = (L[4] - L[1]) * invdz;
    const int qp0 = min(15, max(0, (int)((m0 + 60.0f) * 0.13333334f)));
    const int qp1 = min(15, max(0, (int)((m1 + 60.0f) * 0.13333334f)));
    const int qs0 = min(7,  max(0, (int)((sl0 + 0.75f) * 5.3333335f)));
    const int qs1 = min(7,  max(0, (int)((sl1 + 0.75f) * 5.3333335f)));
    return (((qs0 << 3) | qs1) << 8) | (qp0 << 4) | qp1;
}

__global__ __launch_bounds__(256)
void zero_bins(unsigned* __restrict__ bins, int n)
{
    const int t = blockIdx.x * 256 + threadIdx.x;
    if (t < n) bins[t] = 0u;
}

__global__ __launch_bounds__(256)
void hist_kernel(const float* __restrict__ xl, const float* __restrict__ yl,
                 const float* __restrict__ zl,
                 int nx, int ny, int nz, unsigned* __restrict__ hist)
{
    const int t = blockIdx.x * 256 + threadIdx.x;
    const float* L; int set;
    if (t < nx)                { L = xl + 6 * (size_t)t;              set = 0; }
    else if (t < nx + ny)      { L = yl + 6 * (size_t)(t - nx);       set = 1; }
    else if (t < nx + ny + nz) { L = zl + 6 * (size_t)(t - nx - ny);  set = 2; }
    else return;
    atomicAdd(&hist[set * NBIN_SET + lor_key(L)], 1u);
}

// Exclusive scan of each set's 16384 bins. One 1024-thread block per set.
__global__ __launch_bounds__(1024)
void scan_bins(const unsigned* __restrict__ hist, unsigned* __restrict__ offs)
{
    __shared__ unsigned part[1024];
    const int set = blockIdx.x;
    const unsigned* h = hist + set * NBIN_SET;
    unsigned* o = offs + set * NBIN_SET;
    const int t = threadIdx.x;

    unsigned loc[16];
    unsigned run = 0;
#pragma unroll
    for (int k = 0; k < 16; ++k) { loc[k] = run; run += h[t * 16 + k]; }
    part[t] = run;
    __syncthreads();
    for (int off = 1; off < 1024; off <<= 1) {
        const unsigned v = (t >= off) ? part[t - off] : 0u;
        __syncthreads();
        part[t] += v;
        __syncthreads();
    }
    const unsigned base = (t == 0) ? 0u : part[t - 1];
#pragma unroll
    for (int k = 0; k < 16; ++k) o[t * 16 + k] = base + loc[k];
}

__global__ __launch_bounds__(256)
void scatter_kernel(const float* __restrict__ xl, const float* __restrict__ yl,
                    const float* __restrict__ zl,
                    int nx, int ny, int nz,
                    unsigned* __restrict__ offs, unsigned* __restrict__ perm)
{
    const int t = blockIdx.x * 256 + threadIdx.x;
    const float* L; int set, i, base;
    if (t < nx)                { L = xl + 6 * (size_t)t;             set = 0; i = t;            base = 0;       }
    else if (t < nx + ny)      { L = yl + 6 * (size_t)(t - nx);      set = 1; i = t - nx;       base = nx;      }
    else if (t < nx + ny + nz) { L = zl + 6 * (size_t)(t - nx - ny); set = 2; i = t - nx - ny;  base = nx + ny; }
    else return;
    const unsigned pos = atomicAdd(&offs[set * NBIN_SET + lor_key(L)], 1u);
    perm[base + pos] = (unsigned)i;
}

// ---------------------------------------------------------------------------
// Cooperative fused projection: 32 lanes per LOR (8 LORs per 256-block).
// Block ranges pick the LOR set; sorted perm indirection.
// ---------------------------------------------------------------------------
__global__ __launch_bounds__(256)
void proj_coop(const float* __restrict__ imgZ,
               const float* __restrict__ imgX,
               const float* __restrict__ xlors,
               const float* __restrict__ ylors,
               const float* __restrict__ zlors,
               const float* __restrict__ center,
               const float* __restrict__ size_,
               const unsigned* __restrict__ perm,
               float* __restrict__ out,
               int nx, int ny, int nz,
               int nbx, int nby, int G)
{
    const int b = blockIdx.x;
    const int G2 = G * G;
    const int sub  = threadIdx.x >> 5;   // LOR slot in block (0..7)
    const int lane = threadIdx.x & 31;   // k-chunk index

    const float* img;
    const float* lors;
    float* op;
    int a0, a1, a2, s0, s1;

    if (b < nbx) {            // px: perm (2,0,1), transposed copy
        const int idx = b * 8 + sub;
        if (idx >= nx) return;
        const int i = (int)perm[idx];
        img = imgX; lors = xlors + 6 * (size_t)i;  op = out + i;
        a0 = 2; a1 = 0; a2 = 1;  s0 = G2; s1 = G;
    } else if (b < nbx + nby) {  // py: perm (1,0,2)
        const int idx = (b - nbx) * 8 + sub;
        if (idx >= ny) return;
        const int i = (int)perm[nx + idx];
        img = imgZ; lors = ylors + 6 * (size_t)i;  op = out + nx + i;
        a0 = 1; a1 = 0; a2 = 2;  s0 = G; s1 = G2;
    } else {                     // pz: identity
        const int idx = (b - nbx - nby) * 8 + sub;
        if (idx >= nz) return;
        const int i = (int)perm[nx + ny + idx];
        img = imgZ; lors = zlors + 6 * (size_t)i;  op = out + nx + ny + i;
        a0 = 0; a1 = 1; a2 = 2;  s0 = G2; s1 = G;
    }

    const float S0 = size_[a0], S1 = size_[a1], S2 = size_[a2];
    const float vs0 = S0 / (float)G, vs1 = S1 / (float)G, vs2 = S2 / (float)G;
    const float lo0 = center[a0] - 0.5f * S0;
    const float lo1 = center[a1] - 0.5f * S1;
    const float lo2 = center[a2] - 0.5f * S2;
    const float inv_vs0 = 1.0f / vs0;
    const float inv_vs1 = 1.0f / vs1;

    const float p1x = lors[0], p1y = lors[1], p1z = lors[2];
    const float p2x = lors[3], p2y = lors[4], p2z = lors[5];
    const float dx = p2x - p1x, dy = p2y - p1y, dz = p2z - p1z;
    const float len = sqrtf(dx * dx + dy * dy + dz * dz);
    const float inv_dz = 1.0f / dz;
    const float step = vs2 * len * fabsf(inv_dz);

    // fx(k) = fx0 + k*dfx with fx0 at voxel k=0 center.
    const float t0  = (lo2 + 0.5f * vs2 - p1z) * inv_dz;
    const float dt  = vs2 * inv_dz;
    const float fx0 = (fmaf(t0, dx, p1x) - lo0) * inv_vs0 - 0.5f;
    const float fy0 = (fmaf(t0, dy, p1y) - lo1) * inv_vs1 - 0.5f;
    const float dfx = dt * dx * inv_vs0;
    const float dfy = dt * dy * inv_vs1;

    float partial = 0.0f;
    const int nchunks = G >> 2;          // n2/4
    for (int c = lane; c < nchunks; c += 32)
        partial += tor_chunk(img, fx0, fy0, dfx, dfy, 4 * c, G, G, s0, s1);

    // reduce across the 32 lanes of this LOR (xor masks <32 stay in half-wave)
#pragma unroll
    for (int m = 16; m >= 1; m >>= 1)
        partial += __shfl_xor(partial, m);

    if (lane == 0) *op = partial * step;
}

// Non-cooperative fallback (any G / strides), one thread per LOR.
__global__ __launch_bounds__(256)
void proj_fallback(const float* __restrict__ img,
                   const float* __restrict__ xlors,
                   const float* __restrict__ ylors,
                   const float* __restrict__ zlors,
                   const float* __restrict__ center,
                   const float* __restrict__ size_,
                   float* __restrict__ out,
                   int nx, int ny, int nz,
                   int nbx, int nby, int G)
{
    const int b = blockIdx.x;
    const int G2 = G * G;
    const float* lors; float* op;
    int a0, a1, a2, s0, s1, s2;

    if (b < nbx) {
        const int i = b * 256 + threadIdx.x;
        if (i >= nx) return;
        lors = xlors + 6 * (size_t)i;  op = out + i;
        a0 = 2; a1 = 0; a2 = 1;  s0 = 1; s1 = G2; s2 = G;
    } else if (b < nbx + nby) {
        const int i = (b - nbx) * 256 + threadIdx.x;
        if (i >= ny) return;
        lors = ylors + 6 * (size_t)i;  op = out + nx + i;
        a0 = 1; a1 = 0; a2 = 2;  s0 = G; s1 = G2; s2 = 1;
    } else {
        const int i = (b - nbx - nby) * 256 + threadIdx.x;
        if (i >= nz) return;
        lors = zlors + 6 * (size_t)i;  op = out + nx + ny + i;
        a0 = 0; a1 = 1; a2 = 2;  s0 = G2; s1 = G; s2 = 1;
    }

    const float S0 = size_[a0], S1 = size_[a1], S2 = size_[a2];
    const float vs0 = S0 / (float)G, vs1 = S1 / (float)G, vs2 = S2 / (float)G;
    *op = tor_lor_s(img, lors,
                    center[a0] - 0.5f * S0, center[a1] - 0.5f * S1,
                    center[a2] - 0.5f * S2,
                    vs0, vs1, vs2, G, G, G, s0, s1, s2);
}

// 2D transpose in[R][C] -> out[C][R]; Px[c,i0,i1] = image[i0,i1,c]
// giving the x-perm with strides (G^2, G, 1). R, C divisible by 32.
__global__ __launch_bounds__(256)
void transpose_RC(const float* __restrict__ in, float* __restrict__ outp,
                  int R, int C)
{
    __shared__ float tile[32][33];
    const int rt = blockIdx.x * 32;
    const int ct = blockIdx.y * 32;
    const int tx = threadIdx.x;
    const int ty = threadIdx.y;   // block (32,8)
#pragma unroll
    for (int j = 0; j < 32; j += 8)
        tile[ty + j][tx] = in[(size_t)(rt + ty + j) * C + (ct + tx)];
    __syncthreads();
#pragma unroll
    for (int j = 0; j < 32; j += 8)
        outp[(size_t)(ct + ty + j) * R + (rt + tx)] = tile[tx][ty + j];
}

extern "C" void kernel_launch(void* const* d_in, const int* in_sizes, int n_in,
                              void* d_out, int out_size, void* d_ws, size_t ws_size,
                              hipStream_t stream)
{
    const float* img    = (const float*)d_in[0];
    const float* center = (const float*)d_in[2];
    const float* size_  = (const float*)d_in[3];
    const float* xlors  = (const float*)d_in[4];
    const float* ylors  = (const float*)d_in[5];
    const float* zlors  = (const float*)d_in[6];
    float* out = (float*)d_out;

    const int nx = in_sizes[4] / 6;
    const int ny = in_sizes[5] / 6;
    const int nz = in_sizes[6] / 6;
    const int ntot = nx + ny + nz;

    int G = (int)lround(cbrt((double)in_sizes[0]));
    const int G2 = G * G;

    // Workspace: [Px: G^3 f32][hist: 3*16384 u32][offs: 3*16384 u32][perm: ntot u32]
    const size_t pxBytes   = (size_t)G * G2 * sizeof(float);
    const int    nbins     = 3 * NBIN_SET;
    const size_t needBytes = pxBytes + 2 * (size_t)nbins * sizeof(unsigned)
                           + (size_t)ntot * sizeof(unsigned);
    const bool fast = (G % 32 == 0) && (ws_size >= needBytes);

    if (fast) {
        float*    Px   = (float*)d_ws;
        unsigned* hist = (unsigned*)((char*)d_ws + pxBytes);
        unsigned* offs = hist + nbins;
        unsigned* perm = offs + nbins;

        transpose_RC<<<dim3(G2 / 32, G / 32), dim3(32, 8), 0, stream>>>(
            img, Px, G2, G);

        zero_bins<<<(nbins + 255) / 256, 256, 0, stream>>>(hist, nbins);
        hist_kernel<<<(ntot + 255) / 256, 256, 0, stream>>>(
            xlors, ylors, zlors, nx, ny, nz, hist);
        scan_bins<<<3, 1024, 0, stream>>>(hist, offs);
        scatter_kernel<<<(ntot + 255) / 256, 256, 0, stream>>>(
            xlors, ylors, zlors, nx, ny, nz, offs, perm);

        // 8 LORs per 256-thread block (32 lanes each)
        const int nbx = (nx + 7) / 8;
        const int nby = (ny + 7) / 8;
        const int nbz = (nz + 7) / 8;
        proj_coop<<<nbx + nby + nbz, 256, 0, stream>>>(
            img, Px, xlors, ylors, zlors, center, size_, perm, out,
            nx, ny, nz, nbx, nby, G);
    } else {
        const int nbx = (nx + 255) / 256;
        const int nby = (ny + 255) / 256;
        const int nbz = (nz + 255) / 256;
        proj_fallback<<<nbx + nby + nbz, 256, 0, stream>>>(
            img, xlors, ylors, zlors, center, size_, out,
            nx, ny, nz, nbx, nby, G);
    }
}

// Round 9
// 972.823 us; speedup vs baseline: 2.1278x; 1.2118x over previous
//
#include <hip/hip_runtime.h>
#include <math.h>

// KERNEL_WIDTH = sqrt(9/pi) = 1.6925687506432297
#define KW2_F  2.8647889756541161f   // (9/pi)
#define KW_INV 0.5908179502964271f   // 1/KW
#define RW_F   1.6926f               // slightly >= KW (safe superset bound)

#define NBIN_SET 4096   // position-major 16x16, slope-minor 4x4, per LOR set
#define TPB      512    // slab-kernel block size
#define MAXL     6      // LORs per thread in slab kernel
#define KG       32     // k-slices per block
#define KGC      4      // 128 / KG

__device__ __forceinline__ float fast_sqrtf(float x) {
    return __builtin_amdgcn_sqrtf(x);   // raw v_sqrt_f32, ~1 ulp
}

// ---------------------------------------------------------------------------
// Slab projection kernel. G == 128 only (gated on host).
//
// Geometry (verified against reference permutations):
//   x-set: walks orig axis1; transverse u = orig0 (L[1],L[4]), v = orig2
//          (L[0],L[3]).  Slab = image[:, k, :]  (rows of 512 B, coalesced).
//   y-set: walks orig axis2; u = orig0 (L[1],L[4]), v = orig1 (L[0],L[3]).
//   z-set: walks orig axis2; u = orig0 (L[0],L[3]), v = orig1 (L[1],L[4]).
//          y/z slab = Px[k] plane (contiguous 64 KB), tap = tile[ju][jv].
//
// Per (LOR, k): exact per-k disk superset of the reference 5x5-window taps
// with w>0 (w>0 => dist<KW => |j-round(f)|<=2), w clamped at 0 -> identical
// sum. Taps read from the LDS tile; XOR swizzle (c ^ ((r&7)<<2)) breaks the
// jv%32 bank aliasing of the 128-float row stride.
// ---------------------------------------------------------------------------
__global__ __launch_bounds__(TPB, 4)
void proj_slab(const float* __restrict__ img,
               const float* __restrict__ Px,
               const float* __restrict__ xl,
               const float* __restrict__ yl,
               const float* __restrict__ zl,
               const float* __restrict__ center,
               const float* __restrict__ size_,
               const unsigned* __restrict__ perm,
               float* __restrict__ partial,
               int nx, int ny, int nz, int Sx, int Sb)
{
    const int G = 128, G2 = 128 * 128;
    __shared__ float tile[128 * 128];   // 64 KB

    const int b   = blockIdx.x;
    const int tid = threadIdx.x;
    const int nB  = ny + nz;
    const int ntot = nx + nB;

    int kg, lo, hi, isA;
    if (b < KGC * Sx) {
        isA = 1; kg = b / Sx;
        const int sp = b % Sx;
        const int c  = (nx + Sx - 1) / Sx;
        lo = sp * c; hi = min(nx, lo + c);
    } else {
        isA = 0;
        const int bb = b - KGC * Sx;
        kg = bb / Sb;
        const int sp = bb % Sb;
        const int c  = (nB + Sb - 1) / Sb;
        lo = sp * c; hi = min(nB, lo + c);
    }
    const int k0 = kg * KG;

    // block-uniform geometry (au = 0 for all sets)
    const int av = isA ? 2 : 1;
    const int aw = isA ? 1 : 2;
    const float vsu = size_[0] / (float)G, inv_vsu = 1.0f / vsu;
    const float vsv = size_[av] / (float)G, inv_vsv = 1.0f / vsv;
    const float vsw = size_[aw] / (float)G;
    const float luo = center[0]  - 0.5f * size_[0];
    const float lvo = center[av] - 0.5f * size_[av];
    const float wlo = center[aw] - 0.5f * size_[aw];

    float fu0[MAXL], fv0[MAXL], duk[MAXL], dvk[MAXL], acc[MAXL];

#pragma unroll
    for (int l = 0; l < MAXL; ++l) {
        const int idx = lo + tid + l * TPB;
        acc[l] = 0.0f;
        if (idx < hi) {
            const float* L;
            float pu1, pu2, pv1, pv2;
            if (isA) {
                const unsigned i = perm[idx];
                L = xl + 6 * (size_t)i;
                pu1 = L[1]; pu2 = L[4]; pv1 = L[0]; pv2 = L[3];
            } else if (idx < ny) {
                const unsigned i = perm[nx + idx];
                L = yl + 6 * (size_t)i;
                pu1 = L[1]; pu2 = L[4]; pv1 = L[0]; pv2 = L[3];
            } else {
                const unsigned i = perm[nx + idx];
                L = zl + 6 * (size_t)i;
                pu1 = L[0]; pu2 = L[3]; pv1 = L[1]; pv2 = L[4];
            }
            const float pw1 = L[2], pw2 = L[5];
            const float inv_dw = 1.0f / (pw2 - pw1);
            const float dt = vsw * inv_dw;
            const float t0 = (wlo + 0.5f * vsw - pw1) * inv_dw;
            const float dU = pu2 - pu1, dV = pv2 - pv1;
            fu0[l] = (fmaf(t0, dU, pu1) - luo) * inv_vsu - 0.5f;
            fv0[l] = (fmaf(t0, dV, pv1) - lvo) * inv_vsv - 0.5f;
            duk[l] = dt * dU * inv_vsu;
            dvk[l] = dt * dV * inv_vsv;
        } else {
            fu0[l] = -1e9f; fv0[l] = -1e9f; duk[l] = 0.0f; dvk[l] = 0.0f;
        }
    }

    for (int kk = k0; kk < k0 + KG; ++kk) {
        __syncthreads();   // previous iteration's reads done before overwrite
        if (isA) {
#pragma unroll
            for (int it = 0; it < 8; ++it) {
                const int f = (tid + it * TPB) * 4;   // float index in plane
                const int r = f >> 7, c = f & 127;
                const float4 v = *reinterpret_cast<const float4*>(
                    img + (size_t)r * G2 + kk * G + c);
                const int cs = c ^ ((r & 7) << 2);
                *reinterpret_cast<float4*>(tile + r * 128 + cs) = v;
            }
        } else {
#pragma unroll
            for (int it = 0; it < 8; ++it) {
                const int f = (tid + it * TPB) * 4;
                const int r = f >> 7, c = f & 127;
                const float4 v = *reinterpret_cast<const float4*>(
                    Px + (size_t)kk * G2 + f);
                const int cs = c ^ ((r & 7) << 2);
                *reinterpret_cast<float4*>(tile + r * 128 + cs) = v;
            }
        }
        __syncthreads();

        const float fk = (float)kk;
#pragma unroll
        for (int l = 0; l < MAXL; ++l) {
            const float u = fmaf(fk, duk[l], fu0[l]);
            const float v = fmaf(fk, dvk[l], fv0[l]);
            if (u > -RW_F && u < 127.0f + RW_F &&
                v > -RW_F && v < 127.0f + RW_F) {
                const int ulo = max(0,   (int)ceilf (u - RW_F));
                const int uhi = min(127, (int)floorf(u + RW_F));
                float a = acc[l];
                for (int ju = ulo; ju <= uhi; ++ju) {
                    const float dd  = (float)ju - u;
                    const float dd2 = dd * dd;
                    const float rad = fast_sqrtf(fmaxf(KW2_F - dd2, 0.0f));
                    const int vloI = max(0,   (int)ceilf (v - rad));
                    const int vhiI = min(127, (int)floorf(v + rad));
                    const int rb = ju * 128;
                    const int sw = (ju & 7) << 2;
                    for (int jv = vloI; jv <= vhiI; ++jv) {
                        const float dvv = (float)jv - v;
                        const float d2  = fmaf(dvv, dvv, dd2);
                        const float w   =
                            fmaxf(0.0f, fmaf(-fast_sqrtf(d2), KW_INV, 1.0f));
                        a = fmaf(w, tile[rb + (jv ^ sw)], a);
                    }
                }
                acc[l] = a;
            }
        }
    }

#pragma unroll
    for (int l = 0; l < MAXL; ++l) {
        const int idx = lo + tid + l * TPB;
        if (idx < hi) {
            const int sidx = isA ? idx : nx + idx;
            partial[(size_t)kg * ntot + sidx] = acc[l];
        }
    }
}

// Finalize: sum KGC partials, apply step, un-permute.
__global__ __launch_bounds__(256)
void finalize_kernel(const float* __restrict__ xl,
                     const float* __restrict__ yl,
                     const float* __restrict__ zl,
                     const float* __restrict__ size_,
                     const unsigned* __restrict__ perm,
                     const float* __restrict__ partial,
                     float* __restrict__ out,
                     int nx, int ny, int nz, int G)
{
    const int t = blockIdx.x * 256 + threadIdx.x;
    const int ntot = nx + ny + nz;
    if (t >= ntot) return;

    const unsigned i = perm[t];
    const float* L; int obase; float vsw;
    if (t < nx)           { L = xl + 6 * (size_t)i; obase = 0;       vsw = size_[1] / (float)G; }
    else if (t < nx + ny) { L = yl + 6 * (size_t)i; obase = nx;      vsw = size_[2] / (float)G; }
    else                  { L = zl + 6 * (size_t)i; obase = nx + ny; vsw = size_[2] / (float)G; }

    float s = 0.0f;
#pragma unroll
    for (int kg = 0; kg < KGC; ++kg) s += partial[(size_t)kg * ntot + t];

    const float dx = L[3] - L[0], dy = L[4] - L[1], dz = L[5] - L[2];
    const float len = sqrtf(dx * dx + dy * dy + dz * dz);
    out[obase + (int)i] = s * vsw * len / fabsf(dz);
}

// ---------------------------------------------------------------------------
// Counting sort: position-major 16x16 on transverse midpoint (tile locality),
// slope-minor 4x4 (k-range correlation within a wave).
// ---------------------------------------------------------------------------
__device__ __forceinline__ int lor_key(const float* __restrict__ L)
{
    const float m0 = 0.5f * (L[0] + L[3]);
    const float m1 = 0.5f * (L[1] + L[4]);
    const float invdz = 1.0f / (L[5] - L[2]);
    const float sl0 = (L[3] - L[0]) * invdz;
    const float sl1 = (L[4] - L[1]) * invdz;
    const int qp0 = min(15, max(0, (int)((m0 + 60.0f) * 0.13333334f)));
    const int qp1 = min(15, max(0, (int)((m1 + 60.0f) * 0.13333334f)));
    const int qs0 = min(3,  max(0, (int)((sl0 + 0.75f) * 2.6666667f)));
    const int qs1 = min(3,  max(0, (int)((sl1 + 0.75f) * 2.6666667f)));
    return (((qp0 << 4) | qp1) << 4) | (qs0 << 2) | qs1;
}

__global__ __launch_bounds__(256)
void zero_bins(unsigned* __restrict__ bins, int n)
{
    const int t = blockIdx.x * 256 + threadIdx.x;
    if (t < n) bins[t] = 0u;
}

__global__ __launch_bounds__(256)
void hist_kernel(const float* __restrict__ xlp, const float* __restrict__ ylp,
                 const float* __restrict__ zlp,
                 int nx, int ny, int nz, unsigned* __restrict__ hist)
{
    const int t = blockIdx.x * 256 + threadIdx.x;
    const float* L; int set;
    if (t < nx)                { L = xlp + 6 * (size_t)t;              set = 0; }
    else if (t < nx + ny)      { L = ylp + 6 * (size_t)(t - nx);       set = 1; }
    else if (t < nx + ny + nz) { L = zlp + 6 * (size_t)(t - nx - ny);  set = 2; }
    else return;
    atomicAdd(&hist[set * NBIN_SET + lor_key(L)], 1u);
}

// Exclusive scan of each set's 4096 bins. One 1024-thread block per set.
__global__ __launch_bounds__(1024)
void scan_bins(const unsigned* __restrict__ hist, unsigned* __restrict__ offs)
{
    __shared__ unsigned part[1024];
    const int set = blockIdx.x;
    const unsigned* h = hist + set * NBIN_SET;
    unsigned* o = offs + set * NBIN_SET;
    const int t = threadIdx.x;

    unsigned loc[4];
    unsigned run = 0;
#pragma unroll
    for (int k = 0; k < 4; ++k) { loc[k] = run; run += h[t * 4 + k]; }
    part[t] = run;
    __syncthreads();
    for (int off = 1; off < 1024; off <<= 1) {
        const unsigned v = (t >= off) ? part[t - off] : 0u;
        __syncthreads();
        part[t] += v;
        __syncthreads();
    }
    const unsigned base = (t == 0) ? 0u : part[t - 1];
#pragma unroll
    for (int k = 0; k < 4; ++k) o[t * 4 + k] = base + loc[k];
}

__global__ __launch_bounds__(256)
void scatter_kernel(const float* __restrict__ xlp, const float* __restrict__ ylp,
                    const float* __restrict__ zlp,
                    int nx, int ny, int nz,
                    unsigned* __restrict__ offs, unsigned* __restrict__ perm)
{
    const int t = blockIdx.x * 256 + threadIdx.x;
    const float* L; int set, i, base;
    if (t < nx)                { L = xlp + 6 * (size_t)t;             set = 0; i = t;            base = 0;       }
    else if (t < nx + ny)      { L = ylp + 6 * (size_t)(t - nx);      set = 1; i = t - nx;       base = nx;      }
    else if (t < nx + ny + nz) { L = zlp + 6 * (size_t)(t - nx - ny); set = 2; i = t - nx - ny;  base = nx + ny; }
    else return;
    const unsigned pos = atomicAdd(&offs[set * NBIN_SET + lor_key(L)], 1u);
    perm[base + pos] = (unsigned)i;
}

// ---------------------------------------------------------------------------
// Middle-tier fallback (R8 cooperative gather path): 32 lanes per LOR.
// ---------------------------------------------------------------------------
__device__ __forceinline__
float tor_chunk(const float* __restrict__ img,
                float fx0, float fy0, float dfx, float dfy,
                int k0, int n0, int n1, int s0, int s1)
{
    float fx[4], fy[4];
#pragma unroll
    for (int j = 0; j < 4; ++j) {
        fx[j] = fmaf((float)(k0 + j), dfx, fx0);
        fy[j] = fmaf((float)(k0 + j), dfy, fy0);
    }
    const float fxmin = fminf(fx[0], fx[3]), fxmax = fmaxf(fx[0], fx[3]);
    const float fymin = fminf(fy[0], fy[3]), fymax = fmaxf(fy[0], fy[3]);
    const int xlo = max(0,      (int)ceilf (fxmin - RW_F));
    const int xhi = min(n0 - 1, (int)floorf(fxmax + RW_F));

    float acc0 = 0.0f, acc1 = 0.0f, acc2 = 0.0f, acc3 = 0.0f;
    const float* rowp = img + xlo * s0 + k0;
    for (int jx = xlo; jx <= xhi; ++jx, rowp += s0) {
        float ddx2[4];
#pragma unroll
        for (int j = 0; j < 4; ++j) {
            const float dxx = (float)jx - fx[j];
            ddx2[j] = dxx * dxx;
        }
        const float rowmin =
            fminf(fminf(ddx2[0], ddx2[1]), fminf(ddx2[2], ddx2[3]));
        const float rad = fast_sqrtf(fmaxf(KW2_F - rowmin, 0.0f));
        const int ylo = max(0,      (int)ceilf (fymin - rad));
        const int yhi = min(n1 - 1, (int)floorf(fymax + rad));

        const float* p = rowp + ylo * s1;
        for (int jy = ylo; jy <= yhi; ++jy, p += s1) {
            const float4 v = *reinterpret_cast<const float4*>(p);
            float wg[4];
#pragma unroll
            for (int j = 0; j < 4; ++j) {
                const float dyy = (float)jy - fy[j];
                const float d2  = fmaf(dyy, dyy, ddx2[j]);
                wg[j] = fmaxf(0.0f, fmaf(-fast_sqrtf(d2), KW_INV, 1.0f));
            }
            acc0 = fmaf(wg[0], v.x, acc0);
            acc1 = fmaf(wg[1], v.y, acc1);
            acc2 = fmaf(wg[2], v.z, acc2);
            acc3 = fmaf(wg[3], v.w, acc3);
        }
    }
    return (acc0 + acc1) + (acc2 + acc3);
}

__global__ __launch_bounds__(256)
void proj_coop(const float* __restrict__ imgZ,
               const float* __restrict__ imgX,
               const float* __restrict__ xlp,
               const float* __restrict__ ylp,
               const float* __restrict__ zlp,
               const float* __restrict__ center,
               const float* __restrict__ size_,
               const unsigned* __restrict__ perm,
               float* __restrict__ out,
               int nx, int ny, int nz,
               int nbx, int nby, int G)
{
    const int b = blockIdx.x;
    const int G2 = G * G;
    const int sub  = threadIdx.x >> 5;
    const int lane = threadIdx.x & 31;

    const float* img; const float* lors; float* op;
    int a0, a1, a2, s0, s1;

    if (b < nbx) {
        const int idx = b * 8 + sub; if (idx >= nx) return;
        const int i = (int)perm[idx];
        img = imgX; lors = xlp + 6 * (size_t)i;  op = out + i;
        a0 = 2; a1 = 0; a2 = 1;  s0 = G2; s1 = G;
    } else if (b < nbx + nby) {
        const int idx = (b - nbx) * 8 + sub; if (idx >= ny) return;
        const int i = (int)perm[nx + idx];
        img = imgZ; lors = ylp + 6 * (size_t)i;  op = out + nx + i;
        a0 = 1; a1 = 0; a2 = 2;  s0 = G; s1 = G2;
    } else {
        const int idx = (b - nbx - nby) * 8 + sub; if (idx >= nz) return;
        const int i = (int)perm[nx + ny + idx];
        img = imgZ; lors = zlp + 6 * (size_t)i;  op = out + nx + ny + i;
        a0 = 0; a1 = 1; a2 = 2;  s0 = G2; s1 = G;
    }

    const float S0 = size_[a0], S1 = size_[a1], S2 = size_[a2];
    const float vs0 = S0 / (float)G, vs1 = S1 / (float)G, vs2 = S2 / (float)G;
    const float lo0 = center[a0] - 0.5f * S0;
    const float lo1 = center[a1] - 0.5f * S1;
    const float lo2 = center[a2] - 0.5f * S2;
    const float inv_vs0 = 1.0f / vs0, inv_vs1 = 1.0f / vs1;

    const float p1x = lors[0], p1y = lors[1], p1z = lors[2];
    const float p2x = lors[3], p2y = lors[4], p2z = lors[5];
    const float dx = p2x - p1x, dy = p2y - p1y, dz = p2z - p1z;
    const float len = sqrtf(dx * dx + dy * dy + dz * dz);
    const float inv_dz = 1.0f / dz;
    const float step = vs2 * len * fabsf(inv_dz);

    const float t0  = (lo2 + 0.5f * vs2 - p1z) * inv_dz;
    const float dt  = vs2 * inv_dz;
    const float fx0 = (fmaf(t0, dx, p1x) - lo0) * inv_vs0 - 0.5f;
    const float fy0 = (fmaf(t0, dy, p1y) - lo1) * inv_vs1 - 0.5f;
    const float dfx = dt * dx * inv_vs0;
    const float dfy = dt * dy * inv_vs1;

    float partialv = 0.0f;
    const int nchunks = G >> 2;
    for (int c = lane; c < nchunks; c += 32)
        partialv += tor_chunk(img, fx0, fy0, dfx, dfy, 4 * c, G, G, s0, s1);

#pragma unroll
    for (int m = 16; m >= 1; m >>= 1)
        partialv += __shfl_xor(partialv, m);

    if (lane == 0) *op = partialv * step;
}

// Scalar fallback (any G), one thread per LOR.
__device__ __forceinline__
float tor_lor_s(const float* __restrict__ img,
                const float* __restrict__ L,
                float lo0, float lo1, float lo2,
                float vs0, float vs1, float vs2,
                int n0, int n1, int n2, int s0, int s1, int s2)
{
    const float inv_vs0 = 1.0f / vs0, inv_vs1 = 1.0f / vs1;
    const float p1x = L[0], p1y = L[1], p1z = L[2];
    const float p2x = L[3], p2y = L[4], p2z = L[5];
    const float dx = p2x - p1x, dy = p2y - p1y, dz = p2z - p1z;
    const float len = sqrtf(dx * dx + dy * dy + dz * dz);
    const float inv_dz = 1.0f / dz;
    const float step = vs2 * len * fabsf(inv_dz);

    float acc_total = 0.0f;
    for (int k = 0; k < n2; ++k) {
        const float zc = lo2 + ((float)k + 0.5f) * vs2;
        const float t  = (zc - p1z) * inv_dz;
        const float fx = (fmaf(t, dx, p1x) - lo0) * inv_vs0 - 0.5f;
        const float fy = (fmaf(t, dy, p1y) - lo1) * inv_vs1 - 0.5f;
        const int ix = (int)rintf(fx);
        const int iy = (int)rintf(fy);
        const int kb = k * s2;
        float acc = 0.0f;
#pragma unroll
        for (int o0 = -2; o0 <= 2; ++o0) {
            const int jx = ix + o0;
            if ((unsigned)jx >= (unsigned)n0) continue;
            const float dxx  = (float)jx - fx;
            const float ddx2 = dxx * dxx;
            if (ddx2 >= KW2_F) continue;
            const int xb = jx * s0 + kb;
#pragma unroll
            for (int o1 = -2; o1 <= 2; ++o1) {
                const int jy = iy + o1;
                if ((unsigned)jy >= (unsigned)n1) continue;
                const float dyy = (float)jy - fy;
                const float d2  = fmaf(dyy, dyy, ddx2);
                if (d2 < KW2_F) {
                    const float w = fmaf(-fast_sqrtf(d2), KW_INV, 1.0f);
                    acc = fmaf(w, img[xb + jy * s1], acc);
                }
            }
        }
        acc_total += acc;
    }
    return acc_total * step;
}

__global__ __launch_bounds__(256)
void proj_fallback(const float* __restrict__ img,
                   const float* __restrict__ xlp,
                   const float* __restrict__ ylp,
                   const float* __restrict__ zlp,
                   const float* __restrict__ center,
                   const float* __restrict__ size_,
                   float* __restrict__ out,
                   int nx, int ny, int nz,
                   int nbx, int nby, int G)
{
    const int b = blockIdx.x;
    const int G2 = G * G;
    const float* lors; float* op;
    int a0, a1, a2, s0, s1, s2;

    if (b < nbx) {
        const int i = b * 256 + threadIdx.x; if (i >= nx) return;
        lors = xlp + 6 * (size_t)i;  op = out + i;
        a0 = 2; a1 = 0; a2 = 1;  s0 = 1; s1 = G2; s2 = G;
    } else if (b < nbx + nby) {
        const int i = (b - nbx) * 256 + threadIdx.x; if (i >= ny) return;
        lors = ylp + 6 * (size_t)i;  op = out + nx + i;
        a0 = 1; a1 = 0; a2 = 2;  s0 = G; s1 = G2; s2 = 1;
    } else {
        const int i = (b - nbx - nby) * 256 + threadIdx.x; if (i >= nz) return;
        lors = zlp + 6 * (size_t)i;  op = out + nx + ny + i;
        a0 = 0; a1 = 1; a2 = 2;  s0 = G2; s1 = G; s2 = 1;
    }

    const float S0 = size_[a0], S1 = size_[a1], S2 = size_[a2];
    const float vs0 = S0 / (float)G, vs1 = S1 / (float)G, vs2 = S2 / (float)G;
    *op = tor_lor_s(img, lors,
                    center[a0] - 0.5f * S0, center[a1] - 0.5f * S1,
                    center[a2] - 0.5f * S2,
                    vs0, vs1, vs2, G, G, G, s0, s1, s2);
}

// 2D transpose in[R][C] -> out[C][R]; Px[a,i0,i1] = image[i0,i1,a].
__global__ __launch_bounds__(256)
void transpose_RC(const float* __restrict__ in, float* __restrict__ outp,
                  int R, int C)
{
    __shared__ float tile[32][33];
    const int rt = blockIdx.x * 32;
    const int ct = blockIdx.y * 32;
    const int tx = threadIdx.x;
    const int ty = threadIdx.y;   // block (32,8)
#pragma unroll
    for (int j = 0; j < 32; j += 8)
        tile[ty + j][tx] = in[(size_t)(rt + ty + j) * C + (ct + tx)];
    __syncthreads();
#pragma unroll
    for (int j = 0; j < 32; j += 8)
        outp[(size_t)(ct + ty + j) * R + (rt + tx)] = tile[tx][ty + j];
}

extern "C" void kernel_launch(void* const* d_in, const int* in_sizes, int n_in,
                              void* d_out, int out_size, void* d_ws, size_t ws_size,
                              hipStream_t stream)
{
    const float* img    = (const float*)d_in[0];
    const float* center = (const float*)d_in[2];
    const float* size_  = (const float*)d_in[3];
    const float* xlors  = (const float*)d_in[4];
    const float* ylors  = (const float*)d_in[5];
    const float* zlors  = (const float*)d_in[6];
    float* out = (float*)d_out;

    const int nx = in_sizes[4] / 6;
    const int ny = in_sizes[5] / 6;
    const int nz = in_sizes[6] / 6;
    const int ntot = nx + ny + nz;

    int G = (int)lround(cbrt((double)in_sizes[0]));
    const int G2 = G * G;

    // Workspace: [Px G^3 f32][hist 3*4096][offs 3*4096][perm ntot][partial KGC*ntot]
    const size_t pxBytes  = (size_t)G * G2 * sizeof(float);
    const int    nbins    = 3 * NBIN_SET;
    const size_t sortB    = 2 * (size_t)nbins * sizeof(unsigned)
                          + (size_t)ntot * sizeof(unsigned);
    const size_t needSlab = pxBytes + sortB + (size_t)KGC * ntot * sizeof(float);
    const size_t needCoop = pxBytes + sortB;

    const bool slab = (G == 128) && (ws_size >= needSlab);
    const bool coop = !slab && (G % 32 == 0) && (ws_size >= needCoop);

    if (slab || coop) {
        float*    Px   = (float*)d_ws;
        unsigned* hist = (unsigned*)((char*)d_ws + pxBytes);
        unsigned* offs = hist + nbins;
        unsigned* perm = offs + nbins;
        float*    part = (float*)(perm + ntot);

        transpose_RC<<<dim3(G2 / 32, G / 32), dim3(32, 8), 0, stream>>>(
            img, Px, G2, G);

        zero_bins<<<(nbins + 255) / 256, 256, 0, stream>>>(hist, nbins);
        hist_kernel<<<(ntot + 255) / 256, 256, 0, stream>>>(
            xlors, ylors, zlors, nx, ny, nz, hist);
        scan_bins<<<3, 1024, 0, stream>>>(hist, offs);
        scatter_kernel<<<(ntot + 255) / 256, 256, 0, stream>>>(
            xlors, ylors, zlors, nx, ny, nz, offs, perm);

        if (slab) {
            const int cap = TPB * MAXL;
            const int Sx = max(1, (nx + cap - 1) / cap);
            const int Sb = max(1, (ny + nz + cap - 1) / cap);
            proj_slab<<<KGC * (Sx + Sb), TPB, 0, stream>>>(
                img, Px, xlors, ylors, zlors, center, size_, perm, part,
                nx, ny, nz, Sx, Sb);
            finalize_kernel<<<(ntot + 255) / 256, 256, 0, stream>>>(
                xlors, ylors, zlors, size_, perm, part, out, nx, ny, nz, G);
        } else {
            const int nbx = (nx + 7) / 8;
            const int nby = (ny + 7) / 8;
            const int nbz = (nz + 7) / 8;
            proj_coop<<<nbx + nby + nbz, 256, 0, stream>>>(
                img, Px, xlors, ylors, zlors, center, size_, perm, out,
                nx, ny, nz, nbx, nby, G);
        }
    } else {
        const int nbx = (nx + 255) / 256;
        const int nby = (ny + 255) / 256;
        const int nbz = (nz + 255) / 256;
        proj_fallback<<<nbx + nby + nbz, 256, 0, stream>>>(
            img, xlors, ylors, zlors, center, size_, out,
            nx, ny, nz, nbx, nby, G);
    }
}

// Round 10
// 576.775 us; speedup vs baseline: 3.5889x; 1.6867x over previous
//
#include <hip/hip_runtime.h>
#include <math.h>

// KERNEL_WIDTH = sqrt(9/pi) = 1.6925687506432297
#define KW2_F  2.8647889756541161f   // (9/pi)
#define KW_INV 0.5908179502964271f   // 1/KW
#define RW_F   1.6926f               // slightly >= KW (safe superset bound)

#define NBIN_SET 4096   // position-major 16x16, slope-minor 4x4, per LOR set
#define TPB      512    // slab-kernel block size
#define MAXL     6      // LORs per thread in slab kernel
#define KG       16     // k-slices per block
#define KGC      8      // 128 / KG
#define TROW     132    // padded tile row (128 + 4): bank = (4*ju+jv)%32

__device__ __forceinline__ float fast_sqrtf(float x) {
    return __builtin_amdgcn_sqrtf(x);   // raw v_sqrt_f32, ~1 ulp
}

// ---------------------------------------------------------------------------
// Slab projection kernel. G == 128 only (gated on host).
//
// Geometry:
//   x-set: walks orig axis1; u = orig0 (L[1],L[4]), v = orig2 (L[0],L[3]).
//          Slab = image[:, k, :] (rows of 512 B, coalesced).
//   y-set: walks orig axis2; u = orig0 (L[1],L[4]), v = orig1 (L[0],L[3]).
//   z-set: walks orig axis2; u = orig0 (L[0],L[3]), v = orig1 (L[1],L[4]).
//          y/z slab = Px[k] plane (contiguous 64 KB).
//
// Inner loop: FIXED 4x4 window at (ceil(u-RW), ceil(v-RW)). The w>0 disk has
// diameter 2*KW = 3.385 < 4, and ulo <= ceil(u-KW) while ulo+4 > u+KW, so the
// window covers every reference tap with w>0; w clamps at 0 for the rest ->
// identical sum. All lanes run identical straight-line code: no per-row
// sqrt/ceil, no variable trip counts, compile-time LDS offsets.
// ---------------------------------------------------------------------------
__global__ __launch_bounds__(TPB, 4)
void proj_slab(const float* __restrict__ img,
               const float* __restrict__ Px,
               const float* __restrict__ xl,
               const float* __restrict__ yl,
               const float* __restrict__ zl,
               const float* __restrict__ center,
               const float* __restrict__ size_,
               const unsigned* __restrict__ perm,
               float* __restrict__ partial,
               int nx, int ny, int nz, int Sx, int Sb)
{
    const int G = 128, G2 = 128 * 128;
    __shared__ float tile[128 * TROW];   // 67.6 KB -> 2 blocks/CU

    const int b   = blockIdx.x;
    const int tid = threadIdx.x;
    const int nB  = ny + nz;
    const int ntot = nx + nB;

    int kg, lo, hi, isA;
    if (b < KGC * Sx) {
        isA = 1; kg = b / Sx;
        const int sp = b % Sx;
        const int c  = (nx + Sx - 1) / Sx;
        lo = sp * c; hi = min(nx, lo + c);
    } else {
        isA = 0;
        const int bb = b - KGC * Sx;
        kg = bb / Sb;
        const int sp = bb % Sb;
        const int c  = (nB + Sb - 1) / Sb;
        lo = sp * c; hi = min(nB, lo + c);
    }
    const int k0 = kg * KG;

    // block-uniform geometry (au = 0 for all sets)
    const int av = isA ? 2 : 1;
    const int aw = isA ? 1 : 2;
    const float vsu = size_[0] / (float)G, inv_vsu = 1.0f / vsu;
    const float vsv = size_[av] / (float)G, inv_vsv = 1.0f / vsv;
    const float vsw = size_[aw] / (float)G;
    const float luo = center[0]  - 0.5f * size_[0];
    const float lvo = center[av] - 0.5f * size_[av];
    const float wlo = center[aw] - 0.5f * size_[aw];

    float fu0[MAXL], fv0[MAXL], duk[MAXL], dvk[MAXL], acc[MAXL];

#pragma unroll
    for (int l = 0; l < MAXL; ++l) {
        const int idx = lo + tid + l * TPB;
        acc[l] = 0.0f;
        if (idx < hi) {
            const float* L;
            float pu1, pu2, pv1, pv2;
            if (isA) {
                const unsigned i = perm[idx];
                L = xl + 6 * (size_t)i;
                pu1 = L[1]; pu2 = L[4]; pv1 = L[0]; pv2 = L[3];
            } else if (idx < ny) {
                const unsigned i = perm[nx + idx];
                L = yl + 6 * (size_t)i;
                pu1 = L[1]; pu2 = L[4]; pv1 = L[0]; pv2 = L[3];
            } else {
                const unsigned i = perm[nx + idx];
                L = zl + 6 * (size_t)i;
                pu1 = L[0]; pu2 = L[3]; pv1 = L[1]; pv2 = L[4];
            }
            const float pw1 = L[2], pw2 = L[5];
            const float inv_dw = 1.0f / (pw2 - pw1);
            const float dt = vsw * inv_dw;
            const float t0 = (wlo + 0.5f * vsw - pw1) * inv_dw;
            const float dU = pu2 - pu1, dV = pv2 - pv1;
            fu0[l] = (fmaf(t0, dU, pu1) - luo) * inv_vsu - 0.5f;
            fv0[l] = (fmaf(t0, dV, pv1) - lvo) * inv_vsv - 0.5f;
            duk[l] = dt * dU * inv_vsu;
            dvk[l] = dt * dV * inv_vsv;
        } else {
            fu0[l] = -1e9f; fv0[l] = -1e9f; duk[l] = 0.0f; dvk[l] = 0.0f;
        }
    }

    for (int kk = k0; kk < k0 + KG; ++kk) {
        __syncthreads();   // previous iteration's reads done before overwrite
        if (isA) {
#pragma unroll
            for (int it = 0; it < 8; ++it) {
                const int f = (tid + it * TPB) * 4;   // float index in plane
                const int r = f >> 7, c = f & 127;
                const float4 v = *reinterpret_cast<const float4*>(
                    img + (size_t)r * G2 + kk * G + c);
                *reinterpret_cast<float4*>(tile + r * TROW + c) = v;
            }
        } else {
#pragma unroll
            for (int it = 0; it < 8; ++it) {
                const int f = (tid + it * TPB) * 4;
                const int r = f >> 7, c = f & 127;
                const float4 v = *reinterpret_cast<const float4*>(
                    Px + (size_t)kk * G2 + f);
                *reinterpret_cast<float4*>(tile + r * TROW + c) = v;
            }
        }
        __syncthreads();

        const float fk = (float)kk;
#pragma unroll
        for (int l = 0; l < MAXL; ++l) {
            const float u = fmaf(fk, duk[l], fu0[l]);
            const float v = fmaf(fk, dvk[l], fv0[l]);
            const float fulo = ceilf(u - RW_F);
            const float fvlo = ceilf(v - RW_F);
            const int ulo = (int)fulo;
            const int vlo = (int)fvlo;
            float a = acc[l];
            if ((unsigned)ulo <= 124u && (unsigned)vlo <= 124u) {
                // interior fast path: straight-line 16 taps, uniform lanes
                const float du0 = fulo - u, dv0 = fvlo - v;
                float du2[4], dv2[4];
#pragma unroll
                for (int r = 0; r < 4; ++r) {
                    const float dr = du0 + (float)r; du2[r] = dr * dr;
                    const float dc = dv0 + (float)r; dv2[r] = dc * dc;
                }
                const float* tp = tile + (ulo * TROW + vlo);
#pragma unroll
                for (int r = 0; r < 4; ++r) {
#pragma unroll
                    for (int c = 0; c < 4; ++c) {
                        const float d2 = du2[r] + dv2[c];
                        const float w =
                            fmaxf(0.0f, fmaf(-fast_sqrtf(d2), KW_INV, 1.0f));
                        a = fmaf(w, tp[r * TROW + c], a);
                    }
                }
                acc[l] = a;
            } else if (u > -RW_F && u < 127.0f + RW_F &&
                       v > -RW_F && v < 127.0f + RW_F) {
                // edge path: masked taps (rare)
#pragma unroll
                for (int r = 0; r < 4; ++r) {
                    const int ju = ulo + r;
                    const float dd = (float)ju - u;
                    const float dd2 = dd * dd;
                    const int rb = min(max(ju, 0), 127) * TROW;
                    const bool rok = (unsigned)ju < 128u;
#pragma unroll
                    for (int c = 0; c < 4; ++c) {
                        const int jv = vlo + c;
                        const float dvv = (float)jv - v;
                        const float d2 = fmaf(dvv, dvv, dd2);
                        float w =
                            fmaxf(0.0f, fmaf(-fast_sqrtf(d2), KW_INV, 1.0f));
                        if (!(rok && (unsigned)jv < 128u)) w = 0.0f;
                        a = fmaf(w, tile[rb + min(max(jv, 0), 127)], a);
                    }
                }
                acc[l] = a;
            }
        }
    }

#pragma unroll
    for (int l = 0; l < MAXL; ++l) {
        const int idx = lo + tid + l * TPB;
        if (idx < hi) {
            const int sidx = isA ? idx : nx + idx;
            partial[(size_t)kg * ntot + sidx] = acc[l];
        }
    }
}

// Finalize: sum KGC partials, apply step, un-permute.
__global__ __launch_bounds__(256)
void finalize_kernel(const float* __restrict__ xl,
                     const float* __restrict__ yl,
                     const float* __restrict__ zl,
                     const float* __restrict__ size_,
                     const unsigned* __restrict__ perm,
                     const float* __restrict__ partial,
                     float* __restrict__ out,
                     int nx, int ny, int nz, int G)
{
    const int t = blockIdx.x * 256 + threadIdx.x;
    const int ntot = nx + ny + nz;
    if (t >= ntot) return;

    const unsigned i = perm[t];
    const float* L; int obase; float vsw;
    if (t < nx)           { L = xl + 6 * (size_t)i; obase = 0;       vsw = size_[1] / (float)G; }
    else if (t < nx + ny) { L = yl + 6 * (size_t)i; obase = nx;      vsw = size_[2] / (float)G; }
    else                  { L = zl + 6 * (size_t)i; obase = nx + ny; vsw = size_[2] / (float)G; }

    float s = 0.0f;
#pragma unroll
    for (int kg = 0; kg < KGC; ++kg) s += partial[(size_t)kg * ntot + t];

    const float dx = L[3] - L[0], dy = L[4] - L[1], dz = L[5] - L[2];
    const float len = sqrtf(dx * dx + dy * dy + dz * dz);
    out[obase + (int)i] = s * vsw * len / fabsf(dz);
}

// ---------------------------------------------------------------------------
// Counting sort: position-major 16x16 on transverse midpoint (tile locality),
// slope-minor 4x4.
// ---------------------------------------------------------------------------
__device__ __forceinline__ int lor_key(const float* __restrict__ L)
{
    const float m0 = 0.5f * (L[0] + L[3]);
    const float m1 = 0.5f * (L[1] + L[4]);
    const float invdz = 1.0f / (L[5] - L[2]);
    const float sl0 = (L[3] - L[0]) * invdz;
    const float sl1 = (L[4] - L[1]) * invdz;
    const int qp0 = min(15, max(0, (int)((m0 + 60.0f) * 0.13333334f)));
    const int qp1 = min(15, max(0, (int)((m1 + 60.0f) * 0.13333334f)));
    const int qs0 = min(3,  max(0, (int)((sl0 + 0.75f) * 2.6666667f)));
    const int qs1 = min(3,  max(0, (int)((sl1 + 0.75f) * 2.6666667f)));
    return (((qp0 << 4) | qp1) << 4) | (qs0 << 2) | qs1;
}

__global__ __launch_bounds__(256)
void zero_bins(unsigned* __restrict__ bins, int n)
{
    const int t = blockIdx.x * 256 + threadIdx.x;
    if (t < n) bins[t] = 0u;
}

__global__ __launch_bounds__(256)
void hist_kernel(const float* __restrict__ xlp, const float* __restrict__ ylp,
                 const float* __restrict__ zlp,
                 int nx, int ny, int nz, unsigned* __restrict__ hist)
{
    const int t = blockIdx.x * 256 + threadIdx.x;
    const float* L; int set;
    if (t < nx)                { L = xlp + 6 * (size_t)t;              set = 0; }
    else if (t < nx + ny)      { L = ylp + 6 * (size_t)(t - nx);       set = 1; }
    else if (t < nx + ny + nz) { L = zlp + 6 * (size_t)(t - nx - ny);  set = 2; }
    else return;
    atomicAdd(&hist[set * NBIN_SET + lor_key(L)], 1u);
}

// Exclusive scan of each set's 4096 bins. One 1024-thread block per set.
__global__ __launch_bounds__(1024)
void scan_bins(const unsigned* __restrict__ hist, unsigned* __restrict__ offs)
{
    __shared__ unsigned part[1024];
    const int set = blockIdx.x;
    const unsigned* h = hist + set * NBIN_SET;
    unsigned* o = offs + set * NBIN_SET;
    const int t = threadIdx.x;

    unsigned loc[4];
    unsigned run = 0;
#pragma unroll
    for (int k = 0; k < 4; ++k) { loc[k] = run; run += h[t * 4 + k]; }
    part[t] = run;
    __syncthreads();
    for (int off = 1; off < 1024; off <<= 1) {
        const unsigned v = (t >= off) ? part[t - off] : 0u;
        __syncthreads();
        part[t] += v;
        __syncthreads();
    }
    const unsigned base = (t == 0) ? 0u : part[t - 1];
#pragma unroll
    for (int k = 0; k < 4; ++k) o[t * 4 + k] = base + loc[k];
}

__global__ __launch_bounds__(256)
void scatter_kernel(const float* __restrict__ xlp, const float* __restrict__ ylp,
                    const float* __restrict__ zlp,
                    int nx, int ny, int nz,
                    unsigned* __restrict__ offs, unsigned* __restrict__ perm)
{
    const int t = blockIdx.x * 256 + threadIdx.x;
    const float* L; int set, i, base;
    if (t < nx)                { L = xlp + 6 * (size_t)t;             set = 0; i = t;            base = 0;       }
    else if (t < nx + ny)      { L = ylp + 6 * (size_t)(t - nx);      set = 1; i = t - nx;       base = nx;      }
    else if (t < nx + ny + nz) { L = zlp + 6 * (size_t)(t - nx - ny); set = 2; i = t - nx - ny;  base = nx + ny; }
    else return;
    const unsigned pos = atomicAdd(&offs[set * NBIN_SET + lor_key(L)], 1u);
    perm[base + pos] = (unsigned)i;
}

// ---------------------------------------------------------------------------
// Middle-tier fallback (cooperative gather path): 32 lanes per LOR.
// ---------------------------------------------------------------------------
__device__ __forceinline__
float tor_chunk(const float* __restrict__ img,
                float fx0, float fy0, float dfx, float dfy,
                int k0, int n0, int n1, int s0, int s1)
{
    float fx[4], fy[4];
#pragma unroll
    for (int j = 0; j < 4; ++j) {
        fx[j] = fmaf((float)(k0 + j), dfx, fx0);
        fy[j] = fmaf((float)(k0 + j), dfy, fy0);
    }
    const float fxmin = fminf(fx[0], fx[3]), fxmax = fmaxf(fx[0], fx[3]);
    const float fymin = fminf(fy[0], fy[3]), fymax = fmaxf(fy[0], fy[3]);
    const int xlo = max(0,      (int)ceilf (fxmin - RW_F));
    const int xhi = min(n0 - 1, (int)floorf(fxmax + RW_F));

    float acc0 = 0.0f, acc1 = 0.0f, acc2 = 0.0f, acc3 = 0.0f;
    const float* rowp = img + xlo * s0 + k0;
    for (int jx = xlo; jx <= xhi; ++jx, rowp += s0) {
        float ddx2[4];
#pragma unroll
        for (int j = 0; j < 4; ++j) {
            const float dxx = (float)jx - fx[j];
            ddx2[j] = dxx * dxx;
        }
        const float rowmin =
            fminf(fminf(ddx2[0], ddx2[1]), fminf(ddx2[2], ddx2[3]));
        const float rad = fast_sqrtf(fmaxf(KW2_F - rowmin, 0.0f));
        const int ylo = max(0,      (int)ceilf (fymin - rad));
        const int yhi = min(n1 - 1, (int)floorf(fymax + rad));

        const float* p = rowp + ylo * s1;
        for (int jy = ylo; jy <= yhi; ++jy, p += s1) {
            const float4 v = *reinterpret_cast<const float4*>(p);
            float wg[4];
#pragma unroll
            for (int j = 0; j < 4; ++j) {
                const float dyy = (float)jy - fy[j];
                const float d2  = fmaf(dyy, dyy, ddx2[j]);
                wg[j] = fmaxf(0.0f, fmaf(-fast_sqrtf(d2), KW_INV, 1.0f));
            }
            acc0 = fmaf(wg[0], v.x, acc0);
            acc1 = fmaf(wg[1], v.y, acc1);
            acc2 = fmaf(wg[2], v.z, acc2);
            acc3 = fmaf(wg[3], v.w, acc3);
        }
    }
    return (acc0 + acc1) + (acc2 + acc3);
}

__global__ __launch_bounds__(256)
void proj_coop(const float* __restrict__ imgZ,
               const float* __restrict__ imgX,
               const float* __restrict__ xlp,
               const float* __restrict__ ylp,
               const float* __restrict__ zlp,
               const float* __restrict__ center,
               const float* __restrict__ size_,
               const unsigned* __restrict__ perm,
               float* __restrict__ out,
               int nx, int ny, int nz,
               int nbx, int nby, int G)
{
    const int b = blockIdx.x;
    const int G2 = G * G;
    const int sub  = threadIdx.x >> 5;
    const int lane = threadIdx.x & 31;

    const float* img; const float* lors; float* op;
    int a0, a1, a2, s0, s1;

    if (b < nbx) {
        const int idx = b * 8 + sub; if (idx >= nx) return;
        const int i = (int)perm[idx];
        img = imgX; lors = xlp + 6 * (size_t)i;  op = out + i;
        a0 = 2; a1 = 0; a2 = 1;  s0 = G2; s1 = G;
    } else if (b < nbx + nby) {
        const int idx = (b - nbx) * 8 + sub; if (idx >= ny) return;
        const int i = (int)perm[nx + idx];
        img = imgZ; lors = ylp + 6 * (size_t)i;  op = out + nx + i;
        a0 = 1; a1 = 0; a2 = 2;  s0 = G; s1 = G2;
    } else {
        const int idx = (b - nbx - nby) * 8 + sub; if (idx >= nz) return;
        const int i = (int)perm[nx + ny + idx];
        img = imgZ; lors = zlp + 6 * (size_t)i;  op = out + nx + ny + i;
        a0 = 0; a1 = 1; a2 = 2;  s0 = G2; s1 = G;
    }

    const float S0 = size_[a0], S1 = size_[a1], S2 = size_[a2];
    const float vs0 = S0 / (float)G, vs1 = S1 / (float)G, vs2 = S2 / (float)G;
    const float lo0 = center[a0] - 0.5f * S0;
    const float lo1 = center[a1] - 0.5f * S1;
    const float lo2 = center[a2] - 0.5f * S2;
    const float inv_vs0 = 1.0f / vs0, inv_vs1 = 1.0f / vs1;

    const float p1x = lors[0], p1y = lors[1], p1z = lors[2];
    const float p2x = lors[3], p2y = lors[4], p2z = lors[5];
    const float dx = p2x - p1x, dy = p2y - p1y, dz = p2z - p1z;
    const float len = sqrtf(dx * dx + dy * dy + dz * dz);
    const float inv_dz = 1.0f / dz;
    const float step = vs2 * len * fabsf(inv_dz);

    const float t0  = (lo2 + 0.5f * vs2 - p1z) * inv_dz;
    const float dt  = vs2 * inv_dz;
    const float fx0 = (fmaf(t0, dx, p1x) - lo0) * inv_vs0 - 0.5f;
    const float fy0 = (fmaf(t0, dy, p1y) - lo1) * inv_vs1 - 0.5f;
    const float dfx = dt * dx * inv_vs0;
    const float dfy = dt * dy * inv_vs1;

    float partialv = 0.0f;
    const int nchunks = G >> 2;
    for (int c = lane; c < nchunks; c += 32)
        partialv += tor_chunk(img, fx0, fy0, dfx, dfy, 4 * c, G, G, s0, s1);

#pragma unroll
    for (int m = 16; m >= 1; m >>= 1)
        partialv += __shfl_xor(partialv, m);

    if (lane == 0) *op = partialv * step;
}

// Scalar fallback (any G), one thread per LOR.
__device__ __forceinline__
float tor_lor_s(const float* __restrict__ img,
                const float* __restrict__ L,
                float lo0, float lo1, float lo2,
                float vs0, float vs1, float vs2,
                int n0, int n1, int n2, int s0, int s1, int s2)
{
    const float inv_vs0 = 1.0f / vs0, inv_vs1 = 1.0f / vs1;
    const float p1x = L[0], p1y = L[1], p1z = L[2];
    const float p2x = L[3], p2y = L[4], p2z = L[5];
    const float dx = p2x - p1x, dy = p2y - p1y, dz = p2z - p1z;
    const float len = sqrtf(dx * dx + dy * dy + dz * dz);
    const float inv_dz = 1.0f / dz;
    const float step = vs2 * len * fabsf(inv_dz);

    float acc_total = 0.0f;
    for (int k = 0; k < n2; ++k) {
        const float zc = lo2 + ((float)k + 0.5f) * vs2;
        const float t  = (zc - p1z) * inv_dz;
        const float fx = (fmaf(t, dx, p1x) - lo0) * inv_vs0 - 0.5f;
        const float fy = (fmaf(t, dy, p1y) - lo1) * inv_vs1 - 0.5f;
        const int ix = (int)rintf(fx);
        const int iy = (int)rintf(fy);
        const int kb = k * s2;
        float acc = 0.0f;
#pragma unroll
        for (int o0 = -2; o0 <= 2; ++o0) {
            const int jx = ix + o0;
            if ((unsigned)jx >= (unsigned)n0) continue;
            const float dxx  = (float)jx - fx;
            const float ddx2 = dxx * dxx;
            if (ddx2 >= KW2_F) continue;
            const int xb = jx * s0 + kb;
#pragma unroll
            for (int o1 = -2; o1 <= 2; ++o1) {
                const int jy = iy + o1;
                if ((unsigned)jy >= (unsigned)n1) continue;
                const float dyy = (float)jy - fy;
                const float d2  = fmaf(dyy, dyy, ddx2);
                if (d2 < KW2_F) {
                    const float w = fmaf(-fast_sqrtf(d2), KW_INV, 1.0f);
                    acc = fmaf(w, img[xb + jy * s1], acc);
                }
            }
        }
        acc_total += acc;
    }
    return acc_total * step;
}

__global__ __launch_bounds__(256)
void proj_fallback(const float* __restrict__ img,
                   const float* __restrict__ xlp,
                   const float* __restrict__ ylp,
                   const float* __restrict__ zlp,
                   const float* __restrict__ center,
                   const float* __restrict__ size_,
                   float* __restrict__ out,
                   int nx, int ny, int nz,
                   int nbx, int nby, int G)
{
    const int b = blockIdx.x;
    const int G2 = G * G;
    const float* lors; float* op;
    int a0, a1, a2, s0, s1, s2;

    if (b < nbx) {
        const int i = b * 256 + threadIdx.x; if (i >= nx) return;
        lors = xlp + 6 * (size_t)i;  op = out + i;
        a0 = 2; a1 = 0; a2 = 1;  s0 = 1; s1 = G2; s2 = G;
    } else if (b < nbx + nby) {
        const int i = (b - nbx) * 256 + threadIdx.x; if (i >= ny) return;
        lors = ylp + 6 * (size_t)i;  op = out + nx + i;
        a0 = 1; a1 = 0; a2 = 2;  s0 = G; s1 = G2; s2 = 1;
    } else {
        const int i = (b - nbx - nby) * 256 + threadIdx.x; if (i >= nz) return;
        lors = zlp + 6 * (size_t)i;  op = out + nx + ny + i;
        a0 = 0; a1 = 1; a2 = 2;  s0 = G2; s1 = G; s2 = 1;
    }

    const float S0 = size_[a0], S1 = size_[a1], S2 = size_[a2];
    const float vs0 = S0 / (float)G, vs1 = S1 / (float)G, vs2 = S2 / (float)G;
    *op = tor_lor_s(img, lors,
                    center[a0] - 0.5f * S0, center[a1] - 0.5f * S1,
                    center[a2] - 0.5f * S2,
                    vs0, vs1, vs2, G, G, G, s0, s1, s2);
}

// 2D transpose in[R][C] -> out[C][R]; Px[a,i0,i1] = image[i0,i1,a].
__global__ __launch_bounds__(256)
void transpose_RC(const float* __restrict__ in, float* __restrict__ outp,
                  int R, int C)
{
    __shared__ float tile[32][33];
    const int rt = blockIdx.x * 32;
    const int ct = blockIdx.y * 32;
    const int tx = threadIdx.x;
    const int ty = threadIdx.y;   // block (32,8)
#pragma unroll
    for (int j = 0; j < 32; j += 8)
        tile[ty + j][tx] = in[(size_t)(rt + ty + j) * C + (ct + tx)];
    __syncthreads();
#pragma unroll
    for (int j = 0; j < 32; j += 8)
        outp[(size_t)(ct + ty + j) * R + (rt + tx)] = tile[tx][ty + j];
}

extern "C" void kernel_launch(void* const* d_in, const int* in_sizes, int n_in,
                              void* d_out, int out_size, void* d_ws, size_t ws_size,
                              hipStream_t stream)
{
    const float* img    = (const float*)d_in[0];
    const float* center = (const float*)d_in[2];
    const float* size_  = (const float*)d_in[3];
    const float* xlors  = (const float*)d_in[4];
    const float* ylors  = (const float*)d_in[5];
    const float* zlors  = (const float*)d_in[6];
    float* out = (float*)d_out;

    const int nx = in_sizes[4] / 6;
    const int ny = in_sizes[5] / 6;
    const int nz = in_sizes[6] / 6;
    const int ntot = nx + ny + nz;

    int G = (int)lround(cbrt((double)in_sizes[0]));
    const int G2 = G * G;

    // Workspace: [Px G^3 f32][hist 3*4096][offs 3*4096][perm ntot][partial KGC*ntot]
    const size_t pxBytes  = (size_t)G * G2 * sizeof(float);
    const int    nbins    = 3 * NBIN_SET;
    const size_t sortB    = 2 * (size_t)nbins * sizeof(unsigned)
                          + (size_t)ntot * sizeof(unsigned);
    const size_t needSlab = pxBytes + sortB + (size_t)KGC * ntot * sizeof(float);
    const size_t needCoop = pxBytes + sortB;

    const bool slab = (G == 128) && (ws_size >= needSlab);
    const bool coop = !slab && (G % 32 == 0) && (ws_size >= needCoop);

    if (slab || coop) {
        float*    Px   = (float*)d_ws;
        unsigned* hist = (unsigned*)((char*)d_ws + pxBytes);
        unsigned* offs = hist + nbins;
        unsigned* perm = offs + nbins;
        float*    part = (float*)(perm + ntot);

        transpose_RC<<<dim3(G2 / 32, G / 32), dim3(32, 8), 0, stream>>>(
            img, Px, G2, G);

        zero_bins<<<(nbins + 255) / 256, 256, 0, stream>>>(hist, nbins);
        hist_kernel<<<(ntot + 255) / 256, 256, 0, stream>>>(
            xlors, ylors, zlors, nx, ny, nz, hist);
        scan_bins<<<3, 1024, 0, stream>>>(hist, offs);
        scatter_kernel<<<(ntot + 255) / 256, 256, 0, stream>>>(
            xlors, ylors, zlors, nx, ny, nz, offs, perm);

        if (slab) {
            const int cap = TPB * MAXL;
            const int Sx = max(1, (nx + cap - 1) / cap);
            const int Sb = max(1, (ny + nz + cap - 1) / cap);
            proj_slab<<<KGC * (Sx + Sb), TPB, 0, stream>>>(
                img, Px, xlors, ylors, zlors, center, size_, perm, part,
                nx, ny, nz, Sx, Sb);
            finalize_kernel<<<(ntot + 255) / 256, 256, 0, stream>>>(
                xlors, ylors, zlors, size_, perm, part, out, nx, ny, nz, G);
        } else {
            const int nbx = (nx + 7) / 8;
            const int nby = (ny + 7) / 8;
            const int nbz = (nz + 7) / 8;
            proj_coop<<<nbx + nby + nbz, 256, 0, stream>>>(
                img, Px, xlors, ylors, zlors, center, size_, perm, out,
                nx, ny, nz, nbx, nby, G);
        }
    } else {
        const int nbx = (nx + 255) / 256;
        const int nby = (ny + 255) / 256;
        const int nbz = (nz + 255) / 256;
        proj_fallback<<<nbx + nby + nbz, 256, 0, stream>>>(
            img, xlors, ylors, zlors, center, size_, out,
            nx, ny, nz, nbx, nby, G);
    }
}

// Round 11
// 557.920 us; speedup vs baseline: 3.7102x; 1.0338x over previous
//
#include <hip/hip_runtime.h>
#include <math.h>

// KERNEL_WIDTH = sqrt(9/pi) = 1.6925687506432297
#define KW2_F  2.8647889756541161f   // (9/pi)
#define KW_INV 0.5908179502964271f   // 1/KW
#define RW_F   1.6926f               // slightly >= KW (safe superset bound)

#define NBIN_SET 4096   // position-major 16x16, slope-minor 4x4, per LOR set
#define TPB      1024   // slab-kernel block size (2 blocks/CU -> 32 waves/CU)
#define MAXL     3      // LORs per thread in slab kernel
#define KG       16     // k-slices per block
#define KGC      8      // 128 / KG
#define TROW     132    // padded tile row (128 + 4)

__device__ __forceinline__ float fast_sqrtf(float x) {
    return __builtin_amdgcn_sqrtf(x);   // raw v_sqrt_f32, ~1 ulp
}

// ---------------------------------------------------------------------------
// Slab projection kernel. G == 128 only (gated on host).
//
// Geometry:
//   x-set: walks orig axis1; u = orig0 (L[1],L[4]), v = orig2 (L[0],L[3]).
//          Slab = image[:, k, :] (rows of 512 B, coalesced).
//   y-set: walks orig axis2; u = orig0 (L[1],L[4]), v = orig1 (L[0],L[3]).
//   z-set: walks orig axis2; u = orig0 (L[0],L[3]), v = orig1 (L[1],L[4]).
//          y/z slab = Px[k] plane (contiguous 64 KB).
//
// Inner loop: FIXED 4x4 window at (ceil(u-RW), ceil(v-RW)). The w>0 disk has
// diameter 2*KW = 3.385 < 4 and ulo <= ceil(u-KW), ulo+3 >= u+KW-1 bound, so
// the window covers every reference tap with w>0; w clamps at 0 for the rest
// -> identical sum. All lanes run identical straight-line code.
// ---------------------------------------------------------------------------
__global__ __launch_bounds__(TPB, 2)
void proj_slab(const float* __restrict__ img,
               const float* __restrict__ Px,
               const float* __restrict__ xl,
               const float* __restrict__ yl,
               const float* __restrict__ zl,
               const float* __restrict__ center,
               const float* __restrict__ size_,
               const unsigned* __restrict__ perm,
               float* __restrict__ partial,
               int nx, int ny, int nz, int Sx, int Sb)
{
    const int G = 128, G2 = 128 * 128;
    __shared__ float tile[128 * TROW];   // 67.6 KB -> 2 blocks/CU

    const int b   = blockIdx.x;
    const int tid = threadIdx.x;
    const int nB  = ny + nz;
    const int ntot = nx + nB;

    int kg, lo, hi, isA;
    if (b < KGC * Sx) {
        isA = 1; kg = b / Sx;
        const int sp = b % Sx;
        const int c  = (nx + Sx - 1) / Sx;
        lo = sp * c; hi = min(nx, lo + c);
    } else {
        isA = 0;
        const int bb = b - KGC * Sx;
        kg = bb / Sb;
        const int sp = bb % Sb;
        const int c  = (nB + Sb - 1) / Sb;
        lo = sp * c; hi = min(nB, lo + c);
    }
    const int k0 = kg * KG;

    // block-uniform geometry (au = 0 for all sets)
    const int av = isA ? 2 : 1;
    const int aw = isA ? 1 : 2;
    const float vsu = size_[0] / (float)G, inv_vsu = 1.0f / vsu;
    const float vsv = size_[av] / (float)G, inv_vsv = 1.0f / vsv;
    const float vsw = size_[aw] / (float)G;
    const float luo = center[0]  - 0.5f * size_[0];
    const float lvo = center[av] - 0.5f * size_[av];
    const float wlo = center[aw] - 0.5f * size_[aw];

    float fu0[MAXL], fv0[MAXL], duk[MAXL], dvk[MAXL], acc[MAXL];

#pragma unroll
    for (int l = 0; l < MAXL; ++l) {
        const int idx = lo + tid + l * TPB;
        acc[l] = 0.0f;
        if (idx < hi) {
            const float* L;
            float pu1, pu2, pv1, pv2;
            if (isA) {
                const unsigned i = perm[idx];
                L = xl + 6 * (size_t)i;
                pu1 = L[1]; pu2 = L[4]; pv1 = L[0]; pv2 = L[3];
            } else if (idx < ny) {
                const unsigned i = perm[nx + idx];
                L = yl + 6 * (size_t)i;
                pu1 = L[1]; pu2 = L[4]; pv1 = L[0]; pv2 = L[3];
            } else {
                const unsigned i = perm[nx + idx];
                L = zl + 6 * (size_t)i;
                pu1 = L[0]; pu2 = L[3]; pv1 = L[1]; pv2 = L[4];
            }
            const float pw1 = L[2], pw2 = L[5];
            const float inv_dw = 1.0f / (pw2 - pw1);
            const float dt = vsw * inv_dw;
            const float t0 = (wlo + 0.5f * vsw - pw1) * inv_dw;
            const float dU = pu2 - pu1, dV = pv2 - pv1;
            fu0[l] = (fmaf(t0, dU, pu1) - luo) * inv_vsu - 0.5f;
            fv0[l] = (fmaf(t0, dV, pv1) - lvo) * inv_vsv - 0.5f;
            duk[l] = dt * dU * inv_vsu;
            dvk[l] = dt * dV * inv_vsv;
        } else {
            fu0[l] = -1e9f; fv0[l] = -1e9f; duk[l] = 0.0f; dvk[l] = 0.0f;
        }
    }

    for (int kk = k0; kk < k0 + KG; ++kk) {
        __syncthreads();   // previous iteration's reads done before overwrite
        if (isA) {
#pragma unroll
            for (int it = 0; it < 4; ++it) {
                const int f = (tid + it * TPB) * 4;   // float index in plane
                const int r = f >> 7, c = f & 127;
                const float4 v = *reinterpret_cast<const float4*>(
                    img + (size_t)r * G2 + kk * G + c);
                *reinterpret_cast<float4*>(tile + r * TROW + c) = v;
            }
        } else {
#pragma unroll
            for (int it = 0; it < 4; ++it) {
                const int f = (tid + it * TPB) * 4;
                const int r = f >> 7, c = f & 127;
                const float4 v = *reinterpret_cast<const float4*>(
                    Px + (size_t)kk * G2 + f);
                *reinterpret_cast<float4*>(tile + r * TROW + c) = v;
            }
        }
        __syncthreads();

        const float fk = (float)kk;
#pragma unroll
        for (int l = 0; l < MAXL; ++l) {
            const float u = fmaf(fk, duk[l], fu0[l]);
            const float v = fmaf(fk, dvk[l], fv0[l]);
            const float fulo = ceilf(u - RW_F);
            const float fvlo = ceilf(v - RW_F);
            const int ulo = (int)fulo;
            const int vlo = (int)fvlo;
            float a = acc[l];
            if ((unsigned)ulo <= 124u && (unsigned)vlo <= 124u) {
                // interior fast path: straight-line 16 taps, uniform lanes
                const float du0 = fulo - u, dv0 = fvlo - v;
                float du2[4], dv2[4];
#pragma unroll
                for (int r = 0; r < 4; ++r) {
                    const float dr = du0 + (float)r; du2[r] = dr * dr;
                    const float dc = dv0 + (float)r; dv2[r] = dc * dc;
                }
                const float* tp = tile + (ulo * TROW + vlo);
#pragma unroll
                for (int r = 0; r < 4; ++r) {
#pragma unroll
                    for (int c = 0; c < 4; ++c) {
                        const float d2 = du2[r] + dv2[c];
                        const float w =
                            fmaxf(0.0f, fmaf(-fast_sqrtf(d2), KW_INV, 1.0f));
                        a = fmaf(w, tp[r * TROW + c], a);
                    }
                }
                acc[l] = a;
            } else if (u > -RW_F && u < 127.0f + RW_F &&
                       v > -RW_F && v < 127.0f + RW_F) {
                // edge path: masked taps (rare)
#pragma unroll
                for (int r = 0; r < 4; ++r) {
                    const int ju = ulo + r;
                    const float dd = (float)ju - u;
                    const float dd2 = dd * dd;
                    const int rb = min(max(ju, 0), 127) * TROW;
                    const bool rok = (unsigned)ju < 128u;
#pragma unroll
                    for (int c = 0; c < 4; ++c) {
                        const int jv = vlo + c;
                        const float dvv = (float)jv - v;
                        const float d2 = fmaf(dvv, dvv, dd2);
                        float w =
                            fmaxf(0.0f, fmaf(-fast_sqrtf(d2), KW_INV, 1.0f));
                        if (!(rok && (unsigned)jv < 128u)) w = 0.0f;
                        a = fmaf(w, tile[rb + min(max(jv, 0), 127)], a);
                    }
                }
                acc[l] = a;
            }
        }
    }

#pragma unroll
    for (int l = 0; l < MAXL; ++l) {
        const int idx = lo + tid + l * TPB;
        if (idx < hi) {
            const int sidx = isA ? idx : nx + idx;
            partial[(size_t)kg * ntot + sidx] = acc[l];
        }
    }
}

// Finalize: sum KGC partials, apply step, un-permute.
__global__ __launch_bounds__(256)
void finalize_kernel(const float* __restrict__ xl,
                     const float* __restrict__ yl,
                     const float* __restrict__ zl,
                     const float* __restrict__ size_,
                     const unsigned* __restrict__ perm,
                     const float* __restrict__ partial,
                     float* __restrict__ out,
                     int nx, int ny, int nz, int G)
{
    const int t = blockIdx.x * 256 + threadIdx.x;
    const int ntot = nx + ny + nz;
    if (t >= ntot) return;

    const unsigned i = perm[t];
    const float* L; int obase; float vsw;
    if (t < nx)           { L = xl + 6 * (size_t)i; obase = 0;       vsw = size_[1] / (float)G; }
    else if (t < nx + ny) { L = yl + 6 * (size_t)i; obase = nx;      vsw = size_[2] / (float)G; }
    else                  { L = zl + 6 * (size_t)i; obase = nx + ny; vsw = size_[2] / (float)G; }

    float s = 0.0f;
#pragma unroll
    for (int kg = 0; kg < KGC; ++kg) s += partial[(size_t)kg * ntot + t];

    const float dx = L[3] - L[0], dy = L[4] - L[1], dz = L[5] - L[2];
    const float len = sqrtf(dx * dx + dy * dy + dz * dz);
    out[obase + (int)i] = s * vsw * len / fabsf(dz);
}

// ---------------------------------------------------------------------------
// Counting sort: position-major 16x16 on transverse midpoint (tile locality),
// slope-minor 4x4.
// ---------------------------------------------------------------------------
__device__ __forceinline__ int lor_key(const float* __restrict__ L)
{
    const float m0 = 0.5f * (L[0] + L[3]);
    const float m1 = 0.5f * (L[1] + L[4]);
    const float invdz = 1.0f / (L[5] - L[2]);
    const float sl0 = (L[3] - L[0]) * invdz;
    const float sl1 = (L[4] - L[1]) * invdz;
    const int qp0 = min(15, max(0, (int)((m0 + 60.0f) * 0.13333334f)));
    const int qp1 = min(15, max(0, (int)((m1 + 60.0f) * 0.13333334f)));
    const int qs0 = min(3,  max(0, (int)((sl0 + 0.75f) * 2.6666667f)));
    const int qs1 = min(3,  max(0, (int)((sl1 + 0.75f) * 2.6666667f)));
    return (((qp0 << 4) | qp1) << 4) | (qs0 << 2) | qs1;
}

__global__ __launch_bounds__(256)
void zero_bins(unsigned* __restrict__ bins, int n)
{
    const int t = blockIdx.x * 256 + threadIdx.x;
    if (t < n) bins[t] = 0u;
}

__global__ __launch_bounds__(256)
void hist_kernel(const float* __restrict__ xlp, const float* __restrict__ ylp,
                 const float* __restrict__ zlp,
                 int nx, int ny, int nz, unsigned* __restrict__ hist)
{
    const int t = blockIdx.x * 256 + threadIdx.x;
    const float* L; int set;
    if (t < nx)                { L = xlp + 6 * (size_t)t;              set = 0; }
    else if (t < nx + ny)      { L = ylp + 6 * (size_t)(t - nx);       set = 1; }
    else if (t < nx + ny + nz) { L = zlp + 6 * (size_t)(t - nx - ny);  set = 2; }
    else return;
    atomicAdd(&hist[set * NBIN_SET + lor_key(L)], 1u);
}

// Exclusive scan of each set's 4096 bins. One 1024-thread block per set.
__global__ __launch_bounds__(1024)
void scan_bins(const unsigned* __restrict__ hist, unsigned* __restrict__ offs)
{
    __shared__ unsigned part[1024];
    const int set = blockIdx.x;
    const unsigned* h = hist + set * NBIN_SET;
    unsigned* o = offs + set * NBIN_SET;
    const int t = threadIdx.x;

    unsigned loc[4];
    unsigned run = 0;
#pragma unroll
    for (int k = 0; k < 4; ++k) { loc[k] = run; run += h[t * 4 + k]; }
    part[t] = run;
    __syncthreads();
    for (int off = 1; off < 1024; off <<= 1) {
        const unsigned v = (t >= off) ? part[t - off] : 0u;
        __syncthreads();
        part[t] += v;
        __syncthreads();
    }
    const unsigned base = (t == 0) ? 0u : part[t - 1];
#pragma unroll
    for (int k = 0; k < 4; ++k) o[t * 4 + k] = base + loc[k];
}

__global__ __launch_bounds__(256)
void scatter_kernel(const float* __restrict__ xlp, const float* __restrict__ ylp,
                    const float* __restrict__ zlp,
                    int nx, int ny, int nz,
                    unsigned* __restrict__ offs, unsigned* __restrict__ perm)
{
    const int t = blockIdx.x * 256 + threadIdx.x;
    const float* L; int set, i, base;
    if (t < nx)                { L = xlp + 6 * (size_t)t;             set = 0; i = t;            base = 0;       }
    else if (t < nx + ny)      { L = ylp + 6 * (size_t)(t - nx);      set = 1; i = t - nx;       base = nx;      }
    else if (t < nx + ny + nz) { L = zlp + 6 * (size_t)(t - nx - ny); set = 2; i = t - nx - ny;  base = nx + ny; }
    else return;
    const unsigned pos = atomicAdd(&offs[set * NBIN_SET + lor_key(L)], 1u);
    perm[base + pos] = (unsigned)i;
}

// ---------------------------------------------------------------------------
// Middle-tier fallback (cooperative gather path): 32 lanes per LOR.
// ---------------------------------------------------------------------------
__device__ __forceinline__
float tor_chunk(const float* __restrict__ img,
                float fx0, float fy0, float dfx, float dfy,
                int k0, int n0, int n1, int s0, int s1)
{
    float fx[4], fy[4];
#pragma unroll
    for (int j = 0; j < 4; ++j) {
        fx[j] = fmaf((float)(k0 + j), dfx, fx0);
        fy[j] = fmaf((float)(k0 + j), dfy, fy0);
    }
    const float fxmin = fminf(fx[0], fx[3]), fxmax = fmaxf(fx[0], fx[3]);
    const float fymin = fminf(fy[0], fy[3]), fymax = fmaxf(fy[0], fy[3]);
    const int xlo = max(0,      (int)ceilf (fxmin - RW_F));
    const int xhi = min(n0 - 1, (int)floorf(fxmax + RW_F));

    float acc0 = 0.0f, acc1 = 0.0f, acc2 = 0.0f, acc3 = 0.0f;
    const float* rowp = img + xlo * s0 + k0;
    for (int jx = xlo; jx <= xhi; ++jx, rowp += s0) {
        float ddx2[4];
#pragma unroll
        for (int j = 0; j < 4; ++j) {
            const float dxx = (float)jx - fx[j];
            ddx2[j] = dxx * dxx;
        }
        const float rowmin =
            fminf(fminf(ddx2[0], ddx2[1]), fminf(ddx2[2], ddx2[3]));
        const float rad = fast_sqrtf(fmaxf(KW2_F - rowmin, 0.0f));
        const int ylo = max(0,      (int)ceilf (fymin - rad));
        const int yhi = min(n1 - 1, (int)floorf(fymax + rad));

        const float* p = rowp + ylo * s1;
        for (int jy = ylo; jy <= yhi; ++jy, p += s1) {
            const float4 v = *reinterpret_cast<const float4*>(p);
            float wg[4];
#pragma unroll
            for (int j = 0; j < 4; ++j) {
                const float dyy = (float)jy - fy[j];
                const float d2  = fmaf(dyy, dyy, ddx2[j]);
                wg[j] = fmaxf(0.0f, fmaf(-fast_sqrtf(d2), KW_INV, 1.0f));
            }
            acc0 = fmaf(wg[0], v.x, acc0);
            acc1 = fmaf(wg[1], v.y, acc1);
            acc2 = fmaf(wg[2], v.z, acc2);
            acc3 = fmaf(wg[3], v.w, acc3);
        }
    }
    return (acc0 + acc1) + (acc2 + acc3);
}

__global__ __launch_bounds__(256)
void proj_coop(const float* __restrict__ imgZ,
               const float* __restrict__ imgX,
               const float* __restrict__ xlp,
               const float* __restrict__ ylp,
               const float* __restrict__ zlp,
               const float* __restrict__ center,
               const float* __restrict__ size_,
               const unsigned* __restrict__ perm,
               float* __restrict__ out,
               int nx, int ny, int nz,
               int nbx, int nby, int G)
{
    const int b = blockIdx.x;
    const int G2 = G * G;
    const int sub  = threadIdx.x >> 5;
    const int lane = threadIdx.x & 31;

    const float* img; const float* lors; float* op;
    int a0, a1, a2, s0, s1;

    if (b < nbx) {
        const int idx = b * 8 + sub; if (idx >= nx) return;
        const int i = (int)perm[idx];
        img = imgX; lors = xlp + 6 * (size_t)i;  op = out + i;
        a0 = 2; a1 = 0; a2 = 1;  s0 = G2; s1 = G;
    } else if (b < nbx + nby) {
        const int idx = (b - nbx) * 8 + sub; if (idx >= ny) return;
        const int i = (int)perm[nx + idx];
        img = imgZ; lors = ylp + 6 * (size_t)i;  op = out + nx + i;
        a0 = 1; a1 = 0; a2 = 2;  s0 = G; s1 = G2;
    } else {
        const int idx = (b - nbx - nby) * 8 + sub; if (idx >= nz) return;
        const int i = (int)perm[nx + ny + idx];
        img = imgZ; lors = zlp + 6 * (size_t)i;  op = out + nx + ny + i;
        a0 = 0; a1 = 1; a2 = 2;  s0 = G2; s1 = G;
    }

    const float S0 = size_[a0], S1 = size_[a1], S2 = size_[a2];
    const float vs0 = S0 / (float)G, vs1 = S1 / (float)G, vs2 = S2 / (float)G;
    const float lo0 = center[a0] - 0.5f * S0;
    const float lo1 = center[a1] - 0.5f * S1;
    const float lo2 = center[a2] - 0.5f * S2;
    const float inv_vs0 = 1.0f / vs0, inv_vs1 = 1.0f / vs1;

    const float p1x = lors[0], p1y = lors[1], p1z = lors[2];
    const float p2x = lors[3], p2y = lors[4], p2z = lors[5];
    const float dx = p2x - p1x, dy = p2y - p1y, dz = p2z - p1z;
    const float len = sqrtf(dx * dx + dy * dy + dz * dz);
    const float inv_dz = 1.0f / dz;
    const float step = vs2 * len * fabsf(inv_dz);

    const float t0  = (lo2 + 0.5f * vs2 - p1z) * inv_dz;
    const float dt  = vs2 * inv_dz;
    const float fx0 = (fmaf(t0, dx, p1x) - lo0) * inv_vs0 - 0.5f;
    const float fy0 = (fmaf(t0, dy, p1y) - lo1) * inv_vs1 - 0.5f;
    const float dfx = dt * dx * inv_vs0;
    const float dfy = dt * dy * inv_vs1;

    float partialv = 0.0f;
    const int nchunks = G >> 2;
    for (int c = lane; c < nchunks; c += 32)
        partialv += tor_chunk(img, fx0, fy0, dfx, dfy, 4 * c, G, G, s0, s1);

#pragma unroll
    for (int m = 16; m >= 1; m >>= 1)
        partialv += __shfl_xor(partialv, m);

    if (lane == 0) *op = partialv * step;
}

// Scalar fallback (any G), one thread per LOR.
__device__ __forceinline__
float tor_lor_s(const float* __restrict__ img,
                const float* __restrict__ L,
                float lo0, float lo1, float lo2,
                float vs0, float vs1, float vs2,
                int n0, int n1, int n2, int s0, int s1, int s2)
{
    const float inv_vs0 = 1.0f / vs0, inv_vs1 = 1.0f / vs1;
    const float p1x = L[0], p1y = L[1], p1z = L[2];
    const float p2x = L[3], p2y = L[4], p2z = L[5];
    const float dx = p2x - p1x, dy = p2y - p1y, dz = p2z - p1z;
    const float len = sqrtf(dx * dx + dy * dy + dz * dz);
    const float inv_dz = 1.0f / dz;
    const float step = vs2 * len * fabsf(inv_dz);

    float acc_total = 0.0f;
    for (int k = 0; k < n2; ++k) {
        const float zc = lo2 + ((float)k + 0.5f) * vs2;
        const float t  = (zc - p1z) * inv_dz;
        const float fx = (fmaf(t, dx, p1x) - lo0) * inv_vs0 - 0.5f;
        const float fy = (fmaf(t, dy, p1y) - lo1) * inv_vs1 - 0.5f;
        const int ix = (int)rintf(fx);
        const int iy = (int)rintf(fy);
        const int kb = k * s2;
        float acc = 0.0f;
#pragma unroll
        for (int o0 = -2; o0 <= 2; ++o0) {
            const int jx = ix + o0;
            if ((unsigned)jx >= (unsigned)n0) continue;
            const float dxx  = (float)jx - fx;
            const float ddx2 = dxx * dxx;
            if (ddx2 >= KW2_F) continue;
            const int xb = jx * s0 + kb;
#pragma unroll
            for (int o1 = -2; o1 <= 2; ++o1) {
                const int jy = iy + o1;
                if ((unsigned)jy >= (unsigned)n1) continue;
                const float dyy = (float)jy - fy;
                const float d2  = fmaf(dyy, dyy, ddx2);
                if (d2 < KW2_F) {
                    const float w = fmaf(-fast_sqrtf(d2), KW_INV, 1.0f);
                    acc = fmaf(w, img[xb + jy * s1], acc);
                }
            }
        }
        acc_total += acc;
    }
    return acc_total * step;
}

__global__ __launch_bounds__(256)
void proj_fallback(const float* __restrict__ img,
                   const float* __restrict__ xlp,
                   const float* __restrict__ ylp,
                   const float* __restrict__ zlp,
                   const float* __restrict__ center,
                   const float* __restrict__ size_,
                   float* __restrict__ out,
                   int nx, int ny, int nz,
                   int nbx, int nby, int G)
{
    const int b = blockIdx.x;
    const int G2 = G * G;
    const float* lors; float* op;
    int a0, a1, a2, s0, s1, s2;

    if (b < nbx) {
        const int i = b * 256 + threadIdx.x; if (i >= nx) return;
        lors = xlp + 6 * (size_t)i;  op = out + i;
        a0 = 2; a1 = 0; a2 = 1;  s0 = 1; s1 = G2; s2 = G;
    } else if (b < nbx + nby) {
        const int i = (b - nbx) * 256 + threadIdx.x; if (i >= ny) return;
        lors = ylp + 6 * (size_t)i;  op = out + nx + i;
        a0 = 1; a1 = 0; a2 = 2;  s0 = G; s1 = G2; s2 = 1;
    } else {
        const int i = (b - nbx - nby) * 256 + threadIdx.x; if (i >= nz) return;
        lors = zlp + 6 * (size_t)i;  op = out + nx + ny + i;
        a0 = 0; a1 = 1; a2 = 2;  s0 = G2; s1 = G; s2 = 1;
    }

    const float S0 = size_[a0], S1 = size_[a1], S2 = size_[a2];
    const float vs0 = S0 / (float)G, vs1 = S1 / (float)G, vs2 = S2 / (float)G;
    *op = tor_lor_s(img, lors,
                    center[a0] - 0.5f * S0, center[a1] - 0.5f * S1,
                    center[a2] - 0.5f * S2,
                    vs0, vs1, vs2, G, G, G, s0, s1, s2);
}

// 2D transpose in[R][C] -> out[C][R]; Px[a,i0,i1] = image[i0,i1,a].
__global__ __launch_bounds__(256)
void transpose_RC(const float* __restrict__ in, float* __restrict__ outp,
                  int R, int C)
{
    __shared__ float tile[32][33];
    const int rt = blockIdx.x * 32;
    const int ct = blockIdx.y * 32;
    const int tx = threadIdx.x;
    const int ty = threadIdx.y;   // block (32,8)
#pragma unroll
    for (int j = 0; j < 32; j += 8)
        tile[ty + j][tx] = in[(size_t)(rt + ty + j) * C + (ct + tx)];
    __syncthreads();
#pragma unroll
    for (int j = 0; j < 32; j += 8)
        outp[(size_t)(ct + ty + j) * R + (rt + tx)] = tile[tx][ty + j];
}

extern "C" void kernel_launch(void* const* d_in, const int* in_sizes, int n_in,
                              void* d_out, int out_size, void* d_ws, size_t ws_size,
                              hipStream_t stream)
{
    const float* img    = (const float*)d_in[0];
    const float* center = (const float*)d_in[2];
    const float* size_  = (const float*)d_in[3];
    const float* xlors  = (const float*)d_in[4];
    const float* ylors  = (const float*)d_in[5];
    const float* zlors  = (const float*)d_in[6];
    float* out = (float*)d_out;

    const int nx = in_sizes[4] / 6;
    const int ny = in_sizes[5] / 6;
    const int nz = in_sizes[6] / 6;
    const int ntot = nx + ny + nz;

    int G = (int)lround(cbrt((double)in_sizes[0]));
    const int G2 = G * G;

    // Workspace: [Px G^3 f32][hist 3*4096][offs 3*4096][perm ntot][partial KGC*ntot]
    const size_t pxBytes  = (size_t)G * G2 * sizeof(float);
    const int    nbins    = 3 * NBIN_SET;
    const size_t sortB    = 2 * (size_t)nbins * sizeof(unsigned)
                          + (size_t)ntot * sizeof(unsigned);
    const size_t needSlab = pxBytes + sortB + (size_t)KGC * ntot * sizeof(float);
    const size_t needCoop = pxBytes + sortB;

    const bool slab = (G == 128) && (ws_size >= needSlab);
    const bool coop = !slab && (G % 32 == 0) && (ws_size >= needCoop);

    if (slab || coop) {
        float*    Px   = (float*)d_ws;
        unsigned* hist = (unsigned*)((char*)d_ws + pxBytes);
        unsigned* offs = hist + nbins;
        unsigned* perm = offs + nbins;
        float*    part = (float*)(perm + ntot);

        transpose_RC<<<dim3(G2 / 32, G / 32), dim3(32, 8), 0, stream>>>(
            img, Px, G2, G);

        zero_bins<<<(nbins + 255) / 256, 256, 0, stream>>>(hist, nbins);
        hist_kernel<<<(ntot + 255) / 256, 256, 0, stream>>>(
            xlors, ylors, zlors, nx, ny, nz, hist);
        scan_bins<<<3, 1024, 0, stream>>>(hist, offs);
        scatter_kernel<<<(ntot + 255) / 256, 256, 0, stream>>>(
            xlors, ylors, zlors, nx, ny, nz, offs, perm);

        if (slab) {
            const int cap = TPB * MAXL;
            const int Sx = max(1, (nx + cap - 1) / cap);
            const int Sb = max(1, (ny + nz + cap - 1) / cap);
            proj_slab<<<KGC * (Sx + Sb), TPB, 0, stream>>>(
                img, Px, xlors, ylors, zlors, center, size_, perm, part,
                nx, ny, nz, Sx, Sb);
            finalize_kernel<<<(ntot + 255) / 256, 256, 0, stream>>>(
                xlors, ylors, zlors, size_, perm, part, out, nx, ny, nz, G);
        } else {
            const int nbx = (nx + 7) / 8;
            const int nby = (ny + 7) / 8;
            const int nbz = (nz + 7) / 8;
            proj_coop<<<nbx + nby + nbz, 256, 0, stream>>>(
                img, Px, xlors, ylors, zlors, center, size_, perm, out,
                nx, ny, nz, nbx, nby, G);
        }
    } else {
        const int nbx = (nx + 255) / 256;
        const int nby = (ny + 255) / 256;
        const int nbz = (nz + 255) / 256;
        proj_fallback<<<nbx + nby + nbz, 256, 0, stream>>>(
            img, xlors, ylors, zlors, center, size_, out,
            nx, ny, nz, nbx, nby, G);
    }
}